// Round 5
// baseline (1613.764 us; speedup 1.0000x reference)
//
#include <hip/hip_runtime.h>
#include <hip/hip_cooperative_groups.h>
#include <math.h>

namespace cg = cooperative_groups;

// EthicalGNN: encoder -> 3x(GAT + BN (+ReLU)) -> mean-pool -> 2 MLP heads.
// R12: cooperative mega-kernel, hardened. R11 failed because the coop launch
// was sized by assumption (1024 blocks) and its error code ignored -> nothing
// ran, output stayed zero (err 0.322 == max|h_ref|). Now: grid is sized from
// hipOccupancyMaxActiveBlocksPerMultiprocessor * numCU, all phases are
// gridDim.x-stride, the launch result is checked, and on any failure we fall
// back to the proven R9 11-dispatch path (338.9us, passing) so the round is
// fail-safe. threadfence around grid.sync as cross-XCD visibility insurance.

#define H4 4  // heads
#define NTHR 256

static __device__ __forceinline__ unsigned short f2bf(float f) {
  unsigned u = __float_as_uint(f);
  u += 0x7fffu + ((u >> 16) & 1u);  // round-to-nearest-even
  return (unsigned short)(u >> 16);
}
static __device__ __forceinline__ float bfh(unsigned u) {  // low bf16 -> f32
  return __uint_as_float(u << 16);
}
static __device__ __forceinline__ float bfl(unsigned u) {  // high bf16 -> f32
  return __uint_as_float(u & 0xffff0000u);
}
static __device__ __forceinline__ float eweight(float a) {
  a = (a > 0.f) ? a : 0.2f * a;  // leaky_relu 0.2
  return __expf(a);
}

struct MegaParams {
  const float* x; const int* e_src; const int* e_dst;
  const float* encW; const float* encb;
  const float* W[3]; const float* as_[3]; const float* ad_[3];
  const float* b_[3]; const float* g_[3]; const float* be_[3];
  const float* m_[3]; const float* v_[3];
  const float* eW1; const float* eb1; const float* eW2; const float* eb2;
  const float* mW1; const float* mb1; const float* mW2; const float* mb2;
  float* out; float* hA; float* hB; unsigned short* xpb;
  float* als; float* ald; float* pas; float* pad;
  int* col; int* rbeg; int* rend; int* cursor; int* counter; float* gpart;
  int N; int E;
};

// ---------------- mega: fused GEMM + attention logits (block-stride) ---------
template <int HC, bool ENC>
static __device__ void gemm_phase(const float* __restrict__ hin,
                                  const float* __restrict__ encW,
                                  const float* __restrict__ encb,
                                  const float* __restrict__ W,
                                  const float* __restrict__ was,
                                  const float* __restrict__ wad,
                                  unsigned short* __restrict__ xpb,
                                  float* __restrict__ als, float* __restrict__ ald,
                                  int N, float* hs, int bid) {
  constexpr int K = 64, NB = 16;
  int tid = threadIdx.x;
  int G = gridDim.x;
  if constexpr (HC == 256) {
    int ntiles = (N + NB - 1) / NB;
    for (int tix = bid; tix < ntiles; tix += G) {
      int n0 = tix * NB;
      for (int idx = tid; idx < NB * K; idx += NTHR) {
        int i = idx >> 6, j = idx & 63;
        int n = n0 + i;
        float a = 0.f;
        if constexpr (ENC) {
          if (n < N) {
            a = encb[j];
#pragma unroll
            for (int k = 0; k < 5; ++k) a += hin[n * 5 + k] * encW[k * 64 + j];
          }
        } else {
          a = (n < N) ? hin[(size_t)n0 * K + idx] : 0.f;
        }
        hs[idx] = a;
      }
      __syncthreads();
      float acc[NB];
#pragma unroll
      for (int i = 0; i < NB; ++i) acc[i] = 0.f;
      for (int k = 0; k < K; k += 4) {
        float w0 = W[(k + 0) * HC + tid];
        float w1 = W[(k + 1) * HC + tid];
        float w2 = W[(k + 2) * HC + tid];
        float w3 = W[(k + 3) * HC + tid];
#pragma unroll
        for (int i = 0; i < NB; ++i) {
          float4 hv = *(const float4*)&hs[i * K + k];
          acc[i] += hv.x * w0 + hv.y * w1 + hv.z * w2 + hv.w * w3;
        }
      }
#pragma unroll
      for (int i = 0; i < NB; ++i) {
        int n = n0 + i;
        if (n < N) xpb[(size_t)n * HC + tid] = f2bf(acc[i]);
      }
      if (tid < NB * H4) {
        int i = tid >> 2, h = tid & 3;
        int n = n0 + i;
        float vs = 0.f, vd = 0.f;
#pragma unroll 8
        for (int k = 0; k < K; ++k) {
          float hv = hs[i * K + k];
          vs += hv * was[k * 4 + h];
          vd += hv * wad[k * 4 + h];
        }
        if (n < N) { als[n * H4 + h] = vs; ald[n * H4 + h] = vd; }
      }
      __syncthreads();
    }
  } else {  // HC == 128: dual 16-node subtiles per 256-thr block
    int sub = tid >> 7, t2 = tid & 127;
    int ntiles = (N + 31) / 32;
    for (int tix = bid; tix < ntiles; tix += G) {
      int n0 = tix * 32;
      for (int idx = tid; idx < 32 * K; idx += NTHR) {
        int n = n0 + (idx >> 6);
        hs[idx] = (n < N) ? hin[(size_t)n0 * K + idx] : 0.f;
      }
      __syncthreads();
      int nb0 = n0 + sub * NB;
      const float* hsub = hs + sub * NB * K;
      float acc[NB];
#pragma unroll
      for (int i = 0; i < NB; ++i) acc[i] = 0.f;
      for (int k = 0; k < K; k += 4) {
        float w0 = W[(k + 0) * HC + t2];
        float w1 = W[(k + 1) * HC + t2];
        float w2 = W[(k + 2) * HC + t2];
        float w3 = W[(k + 3) * HC + t2];
#pragma unroll
        for (int i = 0; i < NB; ++i) {
          float4 hv = *(const float4*)&hsub[i * K + k];
          acc[i] += hv.x * w0 + hv.y * w1 + hv.z * w2 + hv.w * w3;
        }
      }
#pragma unroll
      for (int i = 0; i < NB; ++i) {
        int n = nb0 + i;
        if (n < N) xpb[(size_t)n * HC + t2] = f2bf(acc[i]);
      }
      if (t2 < NB * H4) {
        int i = t2 >> 2, h = t2 & 3;
        int n = nb0 + i;
        float vs = 0.f, vd = 0.f;
#pragma unroll 8
        for (int k = 0; k < K; ++k) {
          float hv = hsub[i * K + k];
          vs += hv * was[k * 4 + h];
          vd += hv * wad[k * 4 + h];
        }
        if (n < N) { als[n * H4 + h] = vs; ald[n * H4 + h] = vd; }
      }
      __syncthreads();
    }
  }
}

// ---------------- mega: gather phase (2 waves/node, 2 nodes/block-iter) ------
template <int C, bool RELU, bool POOL>
static __device__ void gather_phase(const unsigned short* __restrict__ xpb,
                                    const float* __restrict__ als,
                                    const float* __restrict__ ald,
                                    const int* __restrict__ rbeg,
                                    const int* __restrict__ rend,
                                    const int* __restrict__ col,
                                    const float* __restrict__ bias,
                                    const float* __restrict__ g,
                                    const float* __restrict__ be,
                                    const float* __restrict__ m,
                                    const float* __restrict__ v,
                                    float* __restrict__ hout,
                                    float* __restrict__ gpart,
                                    int N, float* smem, int bid) {
  constexpr int HC = H4 * C;
  constexpr int VPL = HC / 64;  // 4 (C=64) or 2 (C=32)
  float* accbuf = smem;               // 2 groups * 64*VPL
  float* sbuf = smem + 2 * 64 * VPL;  // 2 groups * 4
  int wid = threadIdx.x >> 6;
  int grp = wid >> 1, sub = wid & 1;
  int lane = threadIdx.x & 63;
  int h = lane >> 4;
  int G = gridDim.x;
  int niter = (N + 2 * G - 1) / (2 * G);
  for (int it = 0; it < niter; ++it) {
    int n = it * (2 * G) + bid * 2 + grp;
    bool valid = (n < N);
    float s = 0.f;
    float acc[VPL];
#pragma unroll
    for (int i = 0; i < VPL; ++i) acc[i] = 0.f;
    float aldn = 0.f;
    int jb = 0, je = 0;
    if (valid) {
      aldn = ald[n * H4 + h];
      int beg = rbeg[n], end = rend[n];
      int len = end - beg;
      int lenA = (len + 1) >> 1;
      jb = sub ? (beg + lenA) : beg;
      je = sub ? end : (beg + lenA);
    }
    for (int cb = jb; cb < je; cb += 64) {
      int clen = je - cb;
      if (clen > 64) clen = 64;
      int cvec = (lane < clen) ? col[cb + lane] : 0;  // one coalesced load
      for (int t = 0; t < clen; t += 8) {
        int sv[8];
        float av[8];
#pragma unroll
        for (int i = 0; i < 8; ++i) {
          int idx = t + i;
          sv[i] = __shfl(cvec, (idx < clen) ? idx : 0, 64);
        }
#pragma unroll
        for (int i = 0; i < 8; ++i) av[i] = als[sv[i] * H4 + h];
        if constexpr (VPL == 4) {
          uint2 uv[8];
#pragma unroll
          for (int i = 0; i < 8; ++i)
            uv[i] = *(const uint2*)(xpb + (size_t)sv[i] * HC + lane * 4);
#pragma unroll
          for (int i = 0; i < 8; ++i) {
            float e = (t + i < clen) ? eweight(av[i] + aldn) : 0.f;
            s += e;
            acc[0] += e * bfh(uv[i].x);
            acc[1] += e * bfl(uv[i].x);
            acc[2] += e * bfh(uv[i].y);
            acc[3] += e * bfl(uv[i].y);
          }
        } else {
          unsigned uw[8];
#pragma unroll
          for (int i = 0; i < 8; ++i)
            uw[i] = *(const unsigned*)(xpb + (size_t)sv[i] * HC + lane * 2);
#pragma unroll
          for (int i = 0; i < 8; ++i) {
            float e = (t + i < clen) ? eweight(av[i] + aldn) : 0.f;
            s += e;
            acc[0] += e * bfh(uw[i]);
            acc[1] += e * bfl(uw[i]);
          }
        }
      }
    }
    if (valid && sub) {
      if ((lane & 15) == 0) sbuf[grp * 4 + h] = s;
#pragma unroll
      for (int i = 0; i < VPL; ++i) accbuf[grp * 64 * VPL + lane * VPL + i] = acc[i];
    }
    __syncthreads();
    if (valid && !sub) {
      s += sbuf[grp * 4 + h];
#pragma unroll
      for (int i = 0; i < VPL; ++i) acc[i] += accbuf[grp * 64 * VPL + lane * VPL + i];
      float inv = 1.f / (s + 1e-16f);
#pragma unroll
      for (int i = 0; i < VPL; ++i) {
        acc[i] *= inv;
        acc[i] += __shfl_xor(acc[i], 16, 64);  // head sum (bits 4,5 = head)
        acc[i] += __shfl_xor(acc[i], 32, 64);
      }
      if (lane < 16) {
        int c0 = lane * VPL;
        float o[VPL];
#pragma unroll
        for (int i = 0; i < VPL; ++i) {
          int cc = c0 + i;
          float t = acc[i] * (1.f / H4) + bias[cc];
          t = (t - m[cc]) * rsqrtf(v[cc] + 1e-5f) * g[cc] + be[cc];
          if (RELU) t = fmaxf(t, 0.f);
          o[i] = t;
          if (POOL) atomicAdd(&gpart[(n & 255) * 32 + cc], t);
        }
        if constexpr (VPL == 4)
          *(float4*)&hout[(size_t)n * C + c0] = make_float4(o[0], o[1], o[2], o[3]);
        else
          *(float2*)&hout[(size_t)n * C + c0] = make_float2(o[0], o[1]);
      }
    }
    __syncthreads();
  }
}

// ---------------- mega: heads (block 0 only) ---------------------------------
static __device__ void heads_phase(const MegaParams& P, float* smem) {
  float* red = smem;        // 256
  float* z = smem + 256;    // 32
  float* hid = smem + 288;  // 32
  int tid = threadIdx.x;
  int c = tid & 31;
  float s = 0.f;
  for (int b = tid >> 5; b < 256; b += 8) s += P.gpart[b * 32 + c];
  red[tid] = s;
  __syncthreads();
  size_t base = (size_t)P.N * 32;
  if (tid < 32) {
    float t = 0.f;
#pragma unroll
    for (int i = 0; i < 8; ++i) t += red[i * 32 + tid];
    t /= (float)P.N;
    z[tid] = t;
    P.out[base + tid] = t;  // graph_emb
  }
  __syncthreads();
  if (tid < 16) {
    float a = P.eb1[tid], b = P.mb1[tid];
    for (int k = 0; k < 32; ++k) {
      a += z[k] * P.eW1[k * 16 + tid];
      b += z[k] * P.mW1[k * 16 + tid];
    }
    hid[tid] = fmaxf(a, 0.f);
    hid[16 + tid] = fmaxf(b, 0.f);
  }
  __syncthreads();
  if (tid == 0) {
    float a = P.eb2[0];
    for (int k = 0; k < 16; ++k) a += hid[k] * P.eW2[k];
    P.out[base + 32] = 1.f / (1.f + __expf(-a));
  } else if (tid == 1) {
    float a = P.mb2[0];
    for (int k = 0; k < 16; ++k) a += hid[16 + k] * P.mW2[k];
    P.out[base + 33] = 1.f / (1.f + __expf(-a));
  }
}

// ---------------- the mega-kernel --------------------------------------------
__global__ __launch_bounds__(NTHR, 4) void k_mega(MegaParams P) {
  cg::grid_group gg = cg::this_grid();
  __shared__ float smem[2048];  // 8 KB
  const int tid = threadIdx.x, bid = blockIdx.x;
  const int G = gridDim.x;
  const int gstr = G * NTHR;

#define GSYNC() do { __threadfence(); gg.sync(); __threadfence(); } while (0)

  // P0: zero cursor + counter + gpart (contiguous)
  {
    int zn = P.N + 1 + 256 * 32;
    for (int i = bid * NTHR + tid; i < zn; i += gstr) P.cursor[i] = 0;
  }
  GSYNC();

  // P1: degree count
  for (int i = bid * NTHR + tid; i < P.E; i += gstr)
    atomicAdd(&P.cursor[P.e_dst[i]], 1);
  GSYNC();

  // P2: region alloc (wave scan + one atomic per 64-node chunk) + was/wad prep
  {
    int lane = tid & 63, wid = tid >> 6;
    int nch = (P.N + 63) >> 6;
    for (int ch = bid * 4 + wid; ch < nch; ch += G * 4) {
      int gid = ch * 64 + lane;
      int size = (gid < P.N) ? (P.cursor[gid] + 1) : 0;  // +1 self-loop
      int v = size;
#pragma unroll
      for (int off = 1; off < 64; off <<= 1) {
        int t = __shfl_up(v, off, 64);
        if (lane >= off) v += t;
      }
      int tot = __shfl(v, 63, 64);
      int base = 0;
      if (lane == 63) base = atomicAdd(P.counter, tot);
      base = __shfl(base, 63, 64);
      if (gid < P.N) {
        int p = base + v - size;  // exclusive prefix
        P.rbeg[gid] = p;
        P.rend[gid] = p + size;
        P.col[p] = gid;  // self-loop slot
        P.cursor[gid] = p + 1;
      }
    }
    if (bid < 3) {  // was/wad[k,h] = sum_c W[k,h*C+c]*a[h,c]
      int l = bid;
      const float* W = P.W[l];
      const float* ap = P.as_[l];
      const float* dp = P.ad_[l];
      int HC = (l == 2) ? 128 : 256;
      int C = HC / H4;
      int k = tid >> 2, h = tid & 3;
      float vs = 0.f, vd = 0.f;
      for (int c = 0; c < C; ++c) {
        float w = W[k * HC + h * C + c];
        vs += w * ap[h * C + c];
        vd += w * dp[h * C + c];
      }
      P.pas[l * 256 + tid] = vs;
      P.pad[l * 256 + tid] = vd;
    }
  }
  GSYNC();

  // P3: scatter (col) + gemm0 (independent of CSR)
  for (int i = bid * NTHR + tid; i < P.E; i += gstr) {
    int p = atomicAdd(&P.cursor[P.e_dst[i]], 1);
    P.col[p] = P.e_src[i];
  }
  gemm_phase<256, true>(P.x, P.encW, P.encb, P.W[0], P.pas, P.pad,
                        P.xpb, P.als, P.ald, P.N, smem, bid);
  GSYNC();

  gather_phase<64, true, false>(P.xpb, P.als, P.ald, P.rbeg, P.rend, P.col,
                                P.b_[0], P.g_[0], P.be_[0], P.m_[0], P.v_[0],
                                P.hB, P.gpart, P.N, smem, bid);
  GSYNC();

  gemm_phase<256, false>(P.hB, nullptr, nullptr, P.W[1], P.pas + 256, P.pad + 256,
                         P.xpb, P.als, P.ald, P.N, smem, bid);
  GSYNC();

  gather_phase<64, true, false>(P.xpb, P.als, P.ald, P.rbeg, P.rend, P.col,
                                P.b_[1], P.g_[1], P.be_[1], P.m_[1], P.v_[1],
                                P.hA, P.gpart, P.N, smem, bid);
  GSYNC();

  gemm_phase<128, false>(P.hA, nullptr, nullptr, P.W[2], P.pas + 512, P.pad + 512,
                         P.xpb, P.als, P.ald, P.N, smem, bid);
  GSYNC();

  gather_phase<32, false, true>(P.xpb, P.als, P.ald, P.rbeg, P.rend, P.col,
                                P.b_[2], P.g_[2], P.be_[2], P.m_[2], P.v_[2],
                                P.out, P.gpart, P.N, smem, bid);
  GSYNC();

  if (bid == 0) heads_phase(P, smem);
#undef GSYNC
}

// ======================= legacy fallback (R9, proven) ========================
__global__ void k_count(const int* __restrict__ dst, int* __restrict__ deg, int E) {
  int gid = blockIdx.x * blockDim.x + threadIdx.x;
  if (gid < E) atomicAdd(&deg[dst[gid]], 1);
}

__global__ void k_alloc(int* __restrict__ cursor, int* __restrict__ rbeg,
                        int* __restrict__ rend, int* __restrict__ col,
                        int* __restrict__ counter, int N,
                        const float* __restrict__ W0, const float* __restrict__ as0, const float* __restrict__ ad0,
                        const float* __restrict__ W1, const float* __restrict__ as1, const float* __restrict__ ad1,
                        const float* __restrict__ W2, const float* __restrict__ as2, const float* __restrict__ ad2,
                        float* __restrict__ pas, float* __restrict__ pad) {
  int gid = blockIdx.x * blockDim.x + threadIdx.x;
  int lane = threadIdx.x & 63;
  int size = (gid < N) ? (cursor[gid] + 1) : 0;
  int v = size;
#pragma unroll
  for (int off = 1; off < 64; off <<= 1) {
    int t = __shfl_up(v, off, 64);
    if (lane >= off) v += t;
  }
  int tot = __shfl(v, 63, 64);
  int base = 0;
  if (lane == 63) base = atomicAdd(counter, tot);
  base = __shfl(base, 63, 64);
  if (gid < N) {
    int p = base + v - size;
    rbeg[gid] = p;
    rend[gid] = p + size;
    col[p] = gid;
    cursor[gid] = p + 1;
  }
  if (blockIdx.x < 3) {
    int l = blockIdx.x;
    const float* W  = (l == 0) ? W0 : (l == 1) ? W1 : W2;
    const float* ap = (l == 0) ? as0 : (l == 1) ? as1 : as2;
    const float* dp = (l == 0) ? ad0 : (l == 1) ? ad1 : ad2;
    int HC = (l == 2) ? 128 : 256;
    int C  = HC / H4;
    int tid = threadIdx.x;
    int k = tid >> 2, h = tid & 3;
    float vs = 0.f, vd = 0.f;
    for (int c = 0; c < C; ++c) {
      float w = W[k * HC + h * C + c];
      vs += w * ap[h * C + c];
      vd += w * dp[h * C + c];
    }
    pas[l * 256 + tid] = vs;
    pad[l * 256 + tid] = vd;
  }
}

__global__ void k_scatter(const int* __restrict__ src, const int* __restrict__ dst,
                          int* __restrict__ cursor, int* __restrict__ col, int E) {
  int gid = blockIdx.x * blockDim.x + threadIdx.x;
  if (gid < E) {
    int p = atomicAdd(&cursor[dst[gid]], 1);
    col[p] = src[gid];
  }
}

template <int HC, bool ENC>
__global__ void k_gemm_al(const float* __restrict__ hin,
                          const float* __restrict__ encW, const float* __restrict__ encb,
                          const float* __restrict__ W,
                          const float* __restrict__ was, const float* __restrict__ wad,
                          unsigned short* __restrict__ xpb,
                          float* __restrict__ als, float* __restrict__ ald, int N) {
  constexpr int K = 64, NB = 16;
  __shared__ float hs[NB * K];
  int n0 = blockIdx.x * NB;
  int tid = threadIdx.x;
  if (ENC) {
    for (int idx = tid; idx < NB * K; idx += HC) {
      int i = idx >> 6, j = idx & 63;
      int n = n0 + i;
      float a = 0.f;
      if (n < N) {
        a = encb[j];
#pragma unroll
        for (int k = 0; k < 5; ++k) a += hin[n * 5 + k] * encW[k * 64 + j];
      }
      hs[idx] = a;
    }
  } else {
    for (int idx = tid; idx < NB * K; idx += HC) {
      int n = n0 + (idx >> 6);
      hs[idx] = (n < N) ? hin[(size_t)n0 * K + idx] : 0.f;
    }
  }
  __syncthreads();
  float acc[NB];
#pragma unroll
  for (int i = 0; i < NB; ++i) acc[i] = 0.f;
  for (int k = 0; k < K; k += 4) {
    float w0 = W[(k + 0) * HC + tid];
    float w1 = W[(k + 1) * HC + tid];
    float w2 = W[(k + 2) * HC + tid];
    float w3 = W[(k + 3) * HC + tid];
#pragma unroll
    for (int i = 0; i < NB; ++i) {
      float4 hv = *(const float4*)&hs[i * K + k];
      acc[i] += hv.x * w0 + hv.y * w1 + hv.z * w2 + hv.w * w3;
    }
  }
#pragma unroll
  for (int i = 0; i < NB; ++i) {
    int n = n0 + i;
    if (n < N) xpb[(size_t)n * HC + tid] = f2bf(acc[i]);
  }
  if (tid < NB * H4) {
    int i = tid >> 2, h = tid & 3;
    int n = n0 + i;
    float vs = 0.f, vd = 0.f;
#pragma unroll 8
    for (int k = 0; k < K; ++k) {
      float hv = hs[i * K + k];
      vs += hv * was[k * 4 + h];
      vd += hv * wad[k * 4 + h];
    }
    if (n < N) {
      als[n * H4 + h] = vs;
      ald[n * H4 + h] = vd;
    }
  }
}

template <int C, bool RELU, bool POOL>
__global__ __launch_bounds__(128) void k_gather(
    const unsigned short* __restrict__ xpb,
    const float* __restrict__ als, const float* __restrict__ ald,
    const int* __restrict__ rbeg, const int* __restrict__ rend,
    const int* __restrict__ col,
    const float* __restrict__ bias, const float* __restrict__ g,
    const float* __restrict__ be, const float* __restrict__ m,
    const float* __restrict__ v, float* __restrict__ hout,
    float* __restrict__ gpart, int N) {
  constexpr int HC = H4 * C;
  constexpr int VPL = HC / 64;
  __shared__ float accbuf[64 * VPL];
  __shared__ float sbuf[H4];
  int sub = threadIdx.x >> 6;
  int lane = threadIdx.x & 63;
  int n = blockIdx.x;
  int h = lane >> 4;
  float aldn = ald[n * H4 + h];
  int beg = rbeg[n], end = rend[n];
  int len = end - beg;
  int lenA = (len + 1) >> 1;
  int jb = sub ? (beg + lenA) : beg;
  int je = sub ? end : (beg + lenA);

  float s = 0.f;
  float acc[VPL];
#pragma unroll
  for (int i = 0; i < VPL; ++i) acc[i] = 0.f;

  for (int cb = jb; cb < je; cb += 64) {
    int clen = je - cb;
    if (clen > 64) clen = 64;
    int cvec = (lane < clen) ? col[cb + lane] : 0;
    for (int t = 0; t < clen; t += 8) {
      int sv[8];
      float av[8];
#pragma unroll
      for (int i = 0; i < 8; ++i) {
        int idx = t + i;
        sv[i] = __shfl(cvec, (idx < clen) ? idx : 0, 64);
      }
#pragma unroll
      for (int i = 0; i < 8; ++i) av[i] = als[sv[i] * H4 + h];
      if constexpr (VPL == 4) {
        uint2 uv[8];
#pragma unroll
        for (int i = 0; i < 8; ++i)
          uv[i] = *(const uint2*)(xpb + (size_t)sv[i] * HC + lane * 4);
#pragma unroll
        for (int i = 0; i < 8; ++i) {
          float e = (t + i < clen) ? eweight(av[i] + aldn) : 0.f;
          s += e;
          acc[0] += e * bfh(uv[i].x);
          acc[1] += e * bfl(uv[i].x);
          acc[2] += e * bfh(uv[i].y);
          acc[3] += e * bfl(uv[i].y);
        }
      } else {
        unsigned uw[8];
#pragma unroll
        for (int i = 0; i < 8; ++i)
          uw[i] = *(const unsigned*)(xpb + (size_t)sv[i] * HC + lane * 2);
#pragma unroll
        for (int i = 0; i < 8; ++i) {
          float e = (t + i < clen) ? eweight(av[i] + aldn) : 0.f;
          s += e;
          acc[0] += e * bfh(uw[i]);
          acc[1] += e * bfl(uw[i]);
        }
      }
    }
  }

  if (sub) {
    if ((lane & 15) == 0) sbuf[h] = s;
#pragma unroll
    for (int i = 0; i < VPL; ++i) accbuf[lane * VPL + i] = acc[i];
  }
  __syncthreads();
  if (sub) return;
  s += sbuf[h];
#pragma unroll
  for (int i = 0; i < VPL; ++i) acc[i] += accbuf[lane * VPL + i];

  float inv = 1.f / (s + 1e-16f);
#pragma unroll
  for (int i = 0; i < VPL; ++i) {
    acc[i] *= inv;
    acc[i] += __shfl_xor(acc[i], 16, 64);
    acc[i] += __shfl_xor(acc[i], 32, 64);
  }

  if (lane < 16) {
    int c0 = lane * VPL;
    float o[VPL];
#pragma unroll
    for (int i = 0; i < VPL; ++i) {
      int cc = c0 + i;
      float t = acc[i] * (1.f / H4) + bias[cc];
      t = (t - m[cc]) * rsqrtf(v[cc] + 1e-5f) * g[cc] + be[cc];
      if (RELU) t = fmaxf(t, 0.f);
      o[i] = t;
      if (POOL) atomicAdd(&gpart[(blockIdx.x & 255) * 32 + cc], t);
    }
    if constexpr (VPL == 4)
      *(float4*)&hout[(size_t)n * C + c0] = make_float4(o[0], o[1], o[2], o[3]);
    else
      *(float2*)&hout[(size_t)n * C + c0] = make_float2(o[0], o[1]);
  }
}

__global__ void k_heads2(const float* __restrict__ gpart,
                         const float* __restrict__ eW1, const float* __restrict__ eb1,
                         const float* __restrict__ eW2, const float* __restrict__ eb2,
                         const float* __restrict__ mW1, const float* __restrict__ mb1,
                         const float* __restrict__ mW2, const float* __restrict__ mb2,
                         float* __restrict__ out, int N) {
  __shared__ float red[256];
  __shared__ float z[32];
  __shared__ float hid[32];
  int tid = threadIdx.x;
  int c = tid & 31;
  float s = 0.f;
  for (int b = tid >> 5; b < 256; b += 8) s += gpart[b * 32 + c];
  red[tid] = s;
  __syncthreads();
  size_t base = (size_t)N * 32;
  if (tid < 32) {
    float t = 0.f;
#pragma unroll
    for (int i = 0; i < 8; ++i) t += red[i * 32 + tid];
    t /= (float)N;
    z[tid] = t;
    out[base + tid] = t;
  }
  __syncthreads();
  if (tid < 16) {
    float a = eb1[tid], b = mb1[tid];
    for (int k = 0; k < 32; ++k) {
      a += z[k] * eW1[k * 16 + tid];
      b += z[k] * mW1[k * 16 + tid];
    }
    hid[tid] = fmaxf(a, 0.f);
    hid[16 + tid] = fmaxf(b, 0.f);
  }
  __syncthreads();
  if (tid == 0) {
    float a = eb2[0];
    for (int k = 0; k < 16; ++k) a += hid[k] * eW2[k];
    out[base + 32] = 1.f / (1.f + __expf(-a));
  } else if (tid == 1) {
    float a = mb2[0];
    for (int k = 0; k < 16; ++k) a += hid[16 + k] * mW2[k];
    out[base + 33] = 1.f / (1.f + __expf(-a));
  }
}

extern "C" void kernel_launch(void* const* d_in, const int* in_sizes, int n_in,
                              void* d_out, int out_size, void* d_ws, size_t ws_size,
                              hipStream_t stream) {
  const int N = in_sizes[0] / 5;   // x is (N,5)
  const int E = in_sizes[1] / 2;   // edge_index is (2,E)
  const int M = E + N;             // CSR slots incl. self-loops

  MegaParams P;
  P.x = (const float*)d_in[0];
  const int* ei = (const int*)d_in[1];
  P.e_src = ei;
  P.e_dst = ei + E;
  P.encW = (const float*)d_in[2];
  P.encb = (const float*)d_in[3];
  for (int l = 0; l < 3; ++l) {
    const int o = 4 + 8 * l;
    P.W[l]   = (const float*)d_in[o + 0];
    P.as_[l] = (const float*)d_in[o + 1];
    P.ad_[l] = (const float*)d_in[o + 2];
    P.b_[l]  = (const float*)d_in[o + 3];
    P.g_[l]  = (const float*)d_in[o + 4];
    P.be_[l] = (const float*)d_in[o + 5];
    P.m_[l]  = (const float*)d_in[o + 6];
    P.v_[l]  = (const float*)d_in[o + 7];
  }
  P.eW1 = (const float*)d_in[28]; P.eb1 = (const float*)d_in[29];
  P.eW2 = (const float*)d_in[30]; P.eb2 = (const float*)d_in[31];
  P.mW1 = (const float*)d_in[32]; P.mb1 = (const float*)d_in[33];
  P.mW2 = (const float*)d_in[34]; P.mb2 = (const float*)d_in[35];
  P.out = (float*)d_out;
  P.N = N; P.E = E;

  // workspace layout: floats, then int region, then gpart
  float* wf = (float*)d_ws;
  size_t off = 0;
  P.hA = wf + off; off += (size_t)N * 64;
  P.hB = wf + off; off += (size_t)N * 64;
  P.xpb = (unsigned short*)(wf + off); off += (size_t)N * 128;  // N*256 bf16
  P.als = wf + off; off += (size_t)N * 4;
  P.ald = wf + off; off += (size_t)N * 4;
  P.pas = wf + off; off += 3 * 256;
  P.pad = wf + off; off += 3 * 256;
  int* wi = (int*)(wf + off);
  P.col = wi;                        // M
  P.rbeg = P.col + M;                // N
  P.rend = P.rbeg + N;               // N
  P.cursor = P.rend + N;             // N   } contiguous: zeroed in-kernel (mega)
  P.counter = P.cursor + N;          // 1   } or by memset (legacy)
  P.gpart = (float*)(P.counter + 1); // 256*32

  // ---- try the cooperative mega-kernel, properly sized & checked ----
  bool done = false;
  {
    int dev = 0;
    if (hipGetDevice(&dev) == hipSuccess) {
      int numCU = 0, maxPerCU = 0;
      if (hipDeviceGetAttribute(&numCU, hipDeviceAttributeMultiprocessorCount, dev) == hipSuccess &&
          hipOccupancyMaxActiveBlocksPerMultiprocessor(&maxPerCU, (const void*)k_mega, NTHR, 0) == hipSuccess &&
          numCU > 0 && maxPerCU > 0) {
        long nblk = (long)maxPerCU * numCU;
        if (nblk > 2048) nblk = 2048;
        void* args[] = {(void*)&P};
        if (hipLaunchCooperativeKernel((void*)k_mega, dim3((unsigned)nblk), dim3(NTHR),
                                       args, 0, stream) == hipSuccess)
          done = true;
      }
    }
  }
  if (done) return;

  // ---- legacy fallback: proven R9 11-dispatch path ----
  const int T = 256;
  const int gE  = (E + T - 1) / T;
  const int gN  = (N + T - 1) / T;
  const int gGE = (N + 15) / 16;

  hipMemsetAsync(P.cursor, 0, (size_t)(N + 1) * sizeof(int) + 256 * 32 * sizeof(float), stream);
  k_count<<<gE, T, 0, stream>>>(P.e_dst, P.cursor, E);
  k_alloc<<<gN, T, 0, stream>>>(P.cursor, P.rbeg, P.rend, P.col, P.counter, N,
                                P.W[0], P.as_[0], P.ad_[0], P.W[1], P.as_[1], P.ad_[1],
                                P.W[2], P.as_[2], P.ad_[2], P.pas, P.pad);
  k_scatter<<<gE, T, 0, stream>>>(P.e_src, P.e_dst, P.cursor, P.col, E);

  k_gemm_al<256, true><<<gGE, 256, 0, stream>>>(P.x, P.encW, P.encb, P.W[0], P.pas, P.pad,
                                                P.xpb, P.als, P.ald, N);
  k_gather<64, true, false><<<N, 128, 0, stream>>>(P.xpb, P.als, P.ald, P.rbeg, P.rend, P.col,
                                                   P.b_[0], P.g_[0], P.be_[0], P.m_[0], P.v_[0],
                                                   P.hB, P.gpart, N);

  k_gemm_al<256, false><<<gGE, 256, 0, stream>>>(P.hB, P.encW, P.encb, P.W[1], P.pas + 256, P.pad + 256,
                                                 P.xpb, P.als, P.ald, N);
  k_gather<64, true, false><<<N, 128, 0, stream>>>(P.xpb, P.als, P.ald, P.rbeg, P.rend, P.col,
                                                   P.b_[1], P.g_[1], P.be_[1], P.m_[1], P.v_[1],
                                                   P.hA, P.gpart, N);

  k_gemm_al<128, false><<<gGE, 128, 0, stream>>>(P.hA, P.encW, P.encb, P.W[2], P.pas + 512, P.pad + 512,
                                                 P.xpb, P.als, P.ald, N);
  k_gather<32, false, true><<<N, 128, 0, stream>>>(P.xpb, P.als, P.ald, P.rbeg, P.rend, P.col,
                                                   P.b_[2], P.g_[2], P.be_[2], P.m_[2], P.v_[2],
                                                   P.out, P.gpart, N);

  k_heads2<<<1, 256, 0, stream>>>(P.gpart, P.eW1, P.eb1, P.eW2, P.eb2,
                                  P.mW1, P.mb1, P.mW2, P.mb2, P.out, N);
}

// Round 6
// 973.825 us; speedup vs baseline: 1.6571x; 1.6571x over previous
//
#include <hip/hip_runtime.h>
#include <math.h>

// EthicalGNN: encoder -> 3x(GAT + BN (+ReLU)) -> mean-pool -> 2 MLP heads.
// R13: persistent mega-kernel with a CUSTOM grid barrier. R12 proved the
// phases cost only ~115-160us (VALUBusy 4.4% of 2600us) and that cg's
// grid.sync + per-wave threadfences cost ~270us/sync at 2048 blocks. Here:
// monotonic single-counter barrier (one threadfence + one atomicAdd per BLOCK
// per side, spin on device-scope relaxed load with s_sleep backoff, no
// resets), plus a magic-value init handshake (workspace is poisoned every
// replay, so block 0 zeroes the counter and publishes a 64-bit magic before
// any block arrives). Phase bodies byte-identical to R12 (PASSED). Coop
// launch kept for residency guarantee; proven R9 fallback on launch failure.

#define H4 4  // heads
#define NTHR 256
#define BAR_MAGIC 0x9E3779B97F4A7C15ULL

static __device__ __forceinline__ unsigned short f2bf(float f) {
  unsigned u = __float_as_uint(f);
  u += 0x7fffu + ((u >> 16) & 1u);  // round-to-nearest-even
  return (unsigned short)(u >> 16);
}
static __device__ __forceinline__ float bfh(unsigned u) {  // low bf16 -> f32
  return __uint_as_float(u << 16);
}
static __device__ __forceinline__ float bfl(unsigned u) {  // high bf16 -> f32
  return __uint_as_float(u & 0xffff0000u);
}
static __device__ __forceinline__ float eweight(float a) {
  a = (a > 0.f) ? a : 0.2f * a;  // leaky_relu 0.2
  return __expf(a);
}

// Monotonic grid barrier: call number k waits for cnt >= k*gridDim.x.
// One release-fence + one atomicAdd + spin (relaxed device-scope load,
// s_sleep backoff) + one acquire-fence, all by thread 0 of each block.
static __device__ __forceinline__ void gbar(int* cnt, unsigned target) {
  __syncthreads();
  if (threadIdx.x == 0) {
    __threadfence();            // release: my block's writes -> device visible
    atomicAdd(cnt, 1);
    while ((unsigned)__hip_atomic_load(cnt, __ATOMIC_RELAXED,
                                       __HIP_MEMORY_SCOPE_AGENT) < target)
      __builtin_amdgcn_s_sleep(2);
    __threadfence();            // acquire: see other blocks' writes
  }
  __syncthreads();
}

struct MegaParams {
  const float* x; const int* e_src; const int* e_dst;
  const float* encW; const float* encb;
  const float* W[3]; const float* as_[3]; const float* ad_[3];
  const float* b_[3]; const float* g_[3]; const float* be_[3];
  const float* m_[3]; const float* v_[3];
  const float* eW1; const float* eb1; const float* eW2; const float* eb2;
  const float* mW1; const float* mb1; const float* mW2; const float* mb2;
  float* out; float* hA; float* hB; unsigned short* xpb;
  float* als; float* ald; float* pas; float* pad;
  int* col; int* rbeg; int* rend; int* cursor; int* counter; float* gpart;
  int* bar;  // [0:2): ready magic (u64), [2]: barrier counter
  int N; int E;
};

// ---------------- mega: fused GEMM + attention logits (block-stride) ---------
template <int HC, bool ENC>
static __device__ void gemm_phase(const float* __restrict__ hin,
                                  const float* __restrict__ encW,
                                  const float* __restrict__ encb,
                                  const float* __restrict__ W,
                                  const float* __restrict__ was,
                                  const float* __restrict__ wad,
                                  unsigned short* __restrict__ xpb,
                                  float* __restrict__ als, float* __restrict__ ald,
                                  int N, float* hs, int bid) {
  constexpr int K = 64, NB = 16;
  int tid = threadIdx.x;
  int G = gridDim.x;
  if constexpr (HC == 256) {
    int ntiles = (N + NB - 1) / NB;
    for (int tix = bid; tix < ntiles; tix += G) {
      int n0 = tix * NB;
      for (int idx = tid; idx < NB * K; idx += NTHR) {
        int i = idx >> 6, j = idx & 63;
        int n = n0 + i;
        float a = 0.f;
        if constexpr (ENC) {
          if (n < N) {
            a = encb[j];
#pragma unroll
            for (int k = 0; k < 5; ++k) a += hin[n * 5 + k] * encW[k * 64 + j];
          }
        } else {
          a = (n < N) ? hin[(size_t)n0 * K + idx] : 0.f;
        }
        hs[idx] = a;
      }
      __syncthreads();
      float acc[NB];
#pragma unroll
      for (int i = 0; i < NB; ++i) acc[i] = 0.f;
      for (int k = 0; k < K; k += 4) {
        float w0 = W[(k + 0) * HC + tid];
        float w1 = W[(k + 1) * HC + tid];
        float w2 = W[(k + 2) * HC + tid];
        float w3 = W[(k + 3) * HC + tid];
#pragma unroll
        for (int i = 0; i < NB; ++i) {
          float4 hv = *(const float4*)&hs[i * K + k];
          acc[i] += hv.x * w0 + hv.y * w1 + hv.z * w2 + hv.w * w3;
        }
      }
#pragma unroll
      for (int i = 0; i < NB; ++i) {
        int n = n0 + i;
        if (n < N) xpb[(size_t)n * HC + tid] = f2bf(acc[i]);
      }
      if (tid < NB * H4) {
        int i = tid >> 2, h = tid & 3;
        int n = n0 + i;
        float vs = 0.f, vd = 0.f;
#pragma unroll 8
        for (int k = 0; k < K; ++k) {
          float hv = hs[i * K + k];
          vs += hv * was[k * 4 + h];
          vd += hv * wad[k * 4 + h];
        }
        if (n < N) { als[n * H4 + h] = vs; ald[n * H4 + h] = vd; }
      }
      __syncthreads();
    }
  } else {  // HC == 128: dual 16-node subtiles per 256-thr block
    int sub = tid >> 7, t2 = tid & 127;
    int ntiles = (N + 31) / 32;
    for (int tix = bid; tix < ntiles; tix += G) {
      int n0 = tix * 32;
      for (int idx = tid; idx < 32 * K; idx += NTHR) {
        int n = n0 + (idx >> 6);
        hs[idx] = (n < N) ? hin[(size_t)n0 * K + idx] : 0.f;
      }
      __syncthreads();
      int nb0 = n0 + sub * NB;
      const float* hsub = hs + sub * NB * K;
      float acc[NB];
#pragma unroll
      for (int i = 0; i < NB; ++i) acc[i] = 0.f;
      for (int k = 0; k < K; k += 4) {
        float w0 = W[(k + 0) * HC + t2];
        float w1 = W[(k + 1) * HC + t2];
        float w2 = W[(k + 2) * HC + t2];
        float w3 = W[(k + 3) * HC + t2];
#pragma unroll
        for (int i = 0; i < NB; ++i) {
          float4 hv = *(const float4*)&hsub[i * K + k];
          acc[i] += hv.x * w0 + hv.y * w1 + hv.z * w2 + hv.w * w3;
        }
      }
#pragma unroll
      for (int i = 0; i < NB; ++i) {
        int n = nb0 + i;
        if (n < N) xpb[(size_t)n * HC + t2] = f2bf(acc[i]);
      }
      if (t2 < NB * H4) {
        int i = t2 >> 2, h = t2 & 3;
        int n = nb0 + i;
        float vs = 0.f, vd = 0.f;
#pragma unroll 8
        for (int k = 0; k < K; ++k) {
          float hv = hsub[i * K + k];
          vs += hv * was[k * 4 + h];
          vd += hv * wad[k * 4 + h];
        }
        if (n < N) { als[n * H4 + h] = vs; ald[n * H4 + h] = vd; }
      }
      __syncthreads();
    }
  }
}

// ---------------- mega: gather phase (2 waves/node, 2 nodes/block-iter) ------
template <int C, bool RELU, bool POOL>
static __device__ void gather_phase(const unsigned short* __restrict__ xpb,
                                    const float* __restrict__ als,
                                    const float* __restrict__ ald,
                                    const int* __restrict__ rbeg,
                                    const int* __restrict__ rend,
                                    const int* __restrict__ col,
                                    const float* __restrict__ bias,
                                    const float* __restrict__ g,
                                    const float* __restrict__ be,
                                    const float* __restrict__ m,
                                    const float* __restrict__ v,
                                    float* __restrict__ hout,
                                    float* __restrict__ gpart,
                                    int N, float* smem, int bid) {
  constexpr int HC = H4 * C;
  constexpr int VPL = HC / 64;  // 4 (C=64) or 2 (C=32)
  float* accbuf = smem;               // 2 groups * 64*VPL
  float* sbuf = smem + 2 * 64 * VPL;  // 2 groups * 4
  int wid = threadIdx.x >> 6;
  int grp = wid >> 1, sub = wid & 1;
  int lane = threadIdx.x & 63;
  int h = lane >> 4;
  int G = gridDim.x;
  int niter = (N + 2 * G - 1) / (2 * G);
  for (int it = 0; it < niter; ++it) {
    int n = it * (2 * G) + bid * 2 + grp;
    bool valid = (n < N);
    float s = 0.f;
    float acc[VPL];
#pragma unroll
    for (int i = 0; i < VPL; ++i) acc[i] = 0.f;
    float aldn = 0.f;
    int jb = 0, je = 0;
    if (valid) {
      aldn = ald[n * H4 + h];
      int beg = rbeg[n], end = rend[n];
      int len = end - beg;
      int lenA = (len + 1) >> 1;
      jb = sub ? (beg + lenA) : beg;
      je = sub ? end : (beg + lenA);
    }
    for (int cb = jb; cb < je; cb += 64) {
      int clen = je - cb;
      if (clen > 64) clen = 64;
      int cvec = (lane < clen) ? col[cb + lane] : 0;  // one coalesced load
      for (int t = 0; t < clen; t += 8) {
        int sv[8];
        float av[8];
#pragma unroll
        for (int i = 0; i < 8; ++i) {
          int idx = t + i;
          sv[i] = __shfl(cvec, (idx < clen) ? idx : 0, 64);
        }
#pragma unroll
        for (int i = 0; i < 8; ++i) av[i] = als[sv[i] * H4 + h];
        if constexpr (VPL == 4) {
          uint2 uv[8];
#pragma unroll
          for (int i = 0; i < 8; ++i)
            uv[i] = *(const uint2*)(xpb + (size_t)sv[i] * HC + lane * 4);
#pragma unroll
          for (int i = 0; i < 8; ++i) {
            float e = (t + i < clen) ? eweight(av[i] + aldn) : 0.f;
            s += e;
            acc[0] += e * bfh(uv[i].x);
            acc[1] += e * bfl(uv[i].x);
            acc[2] += e * bfh(uv[i].y);
            acc[3] += e * bfl(uv[i].y);
          }
        } else {
          unsigned uw[8];
#pragma unroll
          for (int i = 0; i < 8; ++i)
            uw[i] = *(const unsigned*)(xpb + (size_t)sv[i] * HC + lane * 2);
#pragma unroll
          for (int i = 0; i < 8; ++i) {
            float e = (t + i < clen) ? eweight(av[i] + aldn) : 0.f;
            s += e;
            acc[0] += e * bfh(uw[i]);
            acc[1] += e * bfl(uw[i]);
          }
        }
      }
    }
    if (valid && sub) {
      if ((lane & 15) == 0) sbuf[grp * 4 + h] = s;
#pragma unroll
      for (int i = 0; i < VPL; ++i) accbuf[grp * 64 * VPL + lane * VPL + i] = acc[i];
    }
    __syncthreads();
    if (valid && !sub) {
      s += sbuf[grp * 4 + h];
#pragma unroll
      for (int i = 0; i < VPL; ++i) acc[i] += accbuf[grp * 64 * VPL + lane * VPL + i];
      float inv = 1.f / (s + 1e-16f);
#pragma unroll
      for (int i = 0; i < VPL; ++i) {
        acc[i] *= inv;
        acc[i] += __shfl_xor(acc[i], 16, 64);  // head sum (bits 4,5 = head)
        acc[i] += __shfl_xor(acc[i], 32, 64);
      }
      if (lane < 16) {
        int c0 = lane * VPL;
        float o[VPL];
#pragma unroll
        for (int i = 0; i < VPL; ++i) {
          int cc = c0 + i;
          float t = acc[i] * (1.f / H4) + bias[cc];
          t = (t - m[cc]) * rsqrtf(v[cc] + 1e-5f) * g[cc] + be[cc];
          if (RELU) t = fmaxf(t, 0.f);
          o[i] = t;
          if (POOL) atomicAdd(&gpart[(n & 255) * 32 + cc], t);
        }
        if constexpr (VPL == 4)
          *(float4*)&hout[(size_t)n * C + c0] = make_float4(o[0], o[1], o[2], o[3]);
        else
          *(float2*)&hout[(size_t)n * C + c0] = make_float2(o[0], o[1]);
      }
    }
    __syncthreads();
  }
}

// ---------------- mega: heads (block 0 only) ---------------------------------
static __device__ void heads_phase(const MegaParams& P, float* smem) {
  float* red = smem;        // 256
  float* z = smem + 256;    // 32
  float* hid = smem + 288;  // 32
  int tid = threadIdx.x;
  int c = tid & 31;
  float s = 0.f;
  for (int b = tid >> 5; b < 256; b += 8) s += P.gpart[b * 32 + c];
  red[tid] = s;
  __syncthreads();
  size_t base = (size_t)P.N * 32;
  if (tid < 32) {
    float t = 0.f;
#pragma unroll
    for (int i = 0; i < 8; ++i) t += red[i * 32 + tid];
    t /= (float)P.N;
    z[tid] = t;
    P.out[base + tid] = t;  // graph_emb
  }
  __syncthreads();
  if (tid < 16) {
    float a = P.eb1[tid], b = P.mb1[tid];
    for (int k = 0; k < 32; ++k) {
      a += z[k] * P.eW1[k * 16 + tid];
      b += z[k] * P.mW1[k * 16 + tid];
    }
    hid[tid] = fmaxf(a, 0.f);
    hid[16 + tid] = fmaxf(b, 0.f);
  }
  __syncthreads();
  if (tid == 0) {
    float a = P.eb2[0];
    for (int k = 0; k < 16; ++k) a += hid[k] * P.eW2[k];
    P.out[base + 32] = 1.f / (1.f + __expf(-a));
  } else if (tid == 1) {
    float a = P.mb2[0];
    for (int k = 0; k < 16; ++k) a += hid[16 + k] * P.mW2[k];
    P.out[base + 33] = 1.f / (1.f + __expf(-a));
  }
}

// ---------------- the mega-kernel --------------------------------------------
__global__ __launch_bounds__(NTHR, 4) void k_mega(MegaParams P) {
  __shared__ float smem[2048];  // 8 KB
  const int tid = threadIdx.x, bid = blockIdx.x;
  const int G = gridDim.x;
  const int gstr = G * NTHR;
  unsigned long long* readyp = (unsigned long long*)P.bar;
  int* cntp = P.bar + 2;
  unsigned bgen = 0;

  // Init handshake: workspace is poisoned each replay, so block 0 zeroes the
  // barrier counter and publishes MAGIC; all blocks wait for MAGIC.
  if (bid == 0 && tid == 0) {
    __hip_atomic_store(cntp, 0, __ATOMIC_RELAXED, __HIP_MEMORY_SCOPE_AGENT);
    __threadfence();
    __hip_atomic_store(readyp, BAR_MAGIC, __ATOMIC_RELAXED, __HIP_MEMORY_SCOPE_AGENT);
  }
  if (tid == 0) {
    while (__hip_atomic_load(readyp, __ATOMIC_RELAXED, __HIP_MEMORY_SCOPE_AGENT) != BAR_MAGIC)
      __builtin_amdgcn_s_sleep(2);
    __threadfence();
  }
  __syncthreads();

#define GSYNC() gbar(cntp, (++bgen) * (unsigned)G)

  // P0: zero cursor + counter + gpart (contiguous)
  {
    int zn = P.N + 1 + 256 * 32;
    for (int i = bid * NTHR + tid; i < zn; i += gstr) P.cursor[i] = 0;
  }
  GSYNC();

  // P1: degree count
  for (int i = bid * NTHR + tid; i < P.E; i += gstr)
    atomicAdd(&P.cursor[P.e_dst[i]], 1);
  GSYNC();

  // P2: region alloc (wave scan + one atomic per 64-node chunk) + was/wad prep
  {
    int lane = tid & 63, wid = tid >> 6;
    int nch = (P.N + 63) >> 6;
    for (int ch = bid * 4 + wid; ch < nch; ch += G * 4) {
      int gid = ch * 64 + lane;
      int size = (gid < P.N) ? (P.cursor[gid] + 1) : 0;  // +1 self-loop
      int v = size;
#pragma unroll
      for (int off = 1; off < 64; off <<= 1) {
        int t = __shfl_up(v, off, 64);
        if (lane >= off) v += t;
      }
      int tot = __shfl(v, 63, 64);
      int base = 0;
      if (lane == 63) base = atomicAdd(P.counter, tot);
      base = __shfl(base, 63, 64);
      if (gid < P.N) {
        int p = base + v - size;  // exclusive prefix
        P.rbeg[gid] = p;
        P.rend[gid] = p + size;
        P.col[p] = gid;  // self-loop slot
        P.cursor[gid] = p + 1;
      }
    }
    if (bid < 3) {  // was/wad[k,h] = sum_c W[k,h*C+c]*a[h,c]
      int l = bid;
      const float* W = P.W[l];
      const float* ap = P.as_[l];
      const float* dp = P.ad_[l];
      int HC = (l == 2) ? 128 : 256;
      int C = HC / H4;
      int k = tid >> 2, h = tid & 3;
      float vs = 0.f, vd = 0.f;
      for (int c = 0; c < C; ++c) {
        float w = W[k * HC + h * C + c];
        vs += w * ap[h * C + c];
        vd += w * dp[h * C + c];
      }
      P.pas[l * 256 + tid] = vs;
      P.pad[l * 256 + tid] = vd;
    }
  }
  GSYNC();

  // P3: scatter (col) + gemm0 (independent of CSR)
  for (int i = bid * NTHR + tid; i < P.E; i += gstr) {
    int p = atomicAdd(&P.cursor[P.e_dst[i]], 1);
    P.col[p] = P.e_src[i];
  }
  gemm_phase<256, true>(P.x, P.encW, P.encb, P.W[0], P.pas, P.pad,
                        P.xpb, P.als, P.ald, P.N, smem, bid);
  GSYNC();

  gather_phase<64, true, false>(P.xpb, P.als, P.ald, P.rbeg, P.rend, P.col,
                                P.b_[0], P.g_[0], P.be_[0], P.m_[0], P.v_[0],
                                P.hB, P.gpart, P.N, smem, bid);
  GSYNC();

  gemm_phase<256, false>(P.hB, nullptr, nullptr, P.W[1], P.pas + 256, P.pad + 256,
                         P.xpb, P.als, P.ald, P.N, smem, bid);
  GSYNC();

  gather_phase<64, true, false>(P.xpb, P.als, P.ald, P.rbeg, P.rend, P.col,
                                P.b_[1], P.g_[1], P.be_[1], P.m_[1], P.v_[1],
                                P.hA, P.gpart, P.N, smem, bid);
  GSYNC();

  gemm_phase<128, false>(P.hA, nullptr, nullptr, P.W[2], P.pas + 512, P.pad + 512,
                         P.xpb, P.als, P.ald, P.N, smem, bid);
  GSYNC();

  gather_phase<32, false, true>(P.xpb, P.als, P.ald, P.rbeg, P.rend, P.col,
                                P.b_[2], P.g_[2], P.be_[2], P.m_[2], P.v_[2],
                                P.out, P.gpart, P.N, smem, bid);
  GSYNC();

  if (bid == 0) heads_phase(P, smem);
#undef GSYNC
}

// ======================= legacy fallback (R9, proven) ========================
__global__ void k_count(const int* __restrict__ dst, int* __restrict__ deg, int E) {
  int gid = blockIdx.x * blockDim.x + threadIdx.x;
  if (gid < E) atomicAdd(&deg[dst[gid]], 1);
}

__global__ void k_alloc(int* __restrict__ cursor, int* __restrict__ rbeg,
                        int* __restrict__ rend, int* __restrict__ col,
                        int* __restrict__ counter, int N,
                        const float* __restrict__ W0, const float* __restrict__ as0, const float* __restrict__ ad0,
                        const float* __restrict__ W1, const float* __restrict__ as1, const float* __restrict__ ad1,
                        const float* __restrict__ W2, const float* __restrict__ as2, const float* __restrict__ ad2,
                        float* __restrict__ pas, float* __restrict__ pad) {
  int gid = blockIdx.x * blockDim.x + threadIdx.x;
  int lane = threadIdx.x & 63;
  int size = (gid < N) ? (cursor[gid] + 1) : 0;
  int v = size;
#pragma unroll
  for (int off = 1; off < 64; off <<= 1) {
    int t = __shfl_up(v, off, 64);
    if (lane >= off) v += t;
  }
  int tot = __shfl(v, 63, 64);
  int base = 0;
  if (lane == 63) base = atomicAdd(counter, tot);
  base = __shfl(base, 63, 64);
  if (gid < N) {
    int p = base + v - size;
    rbeg[gid] = p;
    rend[gid] = p + size;
    col[p] = gid;
    cursor[gid] = p + 1;
  }
  if (blockIdx.x < 3) {
    int l = blockIdx.x;
    const float* W  = (l == 0) ? W0 : (l == 1) ? W1 : W2;
    const float* ap = (l == 0) ? as0 : (l == 1) ? as1 : as2;
    const float* dp = (l == 0) ? ad0 : (l == 1) ? ad1 : ad2;
    int HC = (l == 2) ? 128 : 256;
    int C  = HC / H4;
    int tid = threadIdx.x;
    int k = tid >> 2, h = tid & 3;
    float vs = 0.f, vd = 0.f;
    for (int c = 0; c < C; ++c) {
      float w = W[k * HC + h * C + c];
      vs += w * ap[h * C + c];
      vd += w * dp[h * C + c];
    }
    pas[l * 256 + tid] = vs;
    pad[l * 256 + tid] = vd;
  }
}

__global__ void k_scatter(const int* __restrict__ src, const int* __restrict__ dst,
                          int* __restrict__ cursor, int* __restrict__ col, int E) {
  int gid = blockIdx.x * blockDim.x + threadIdx.x;
  if (gid < E) {
    int p = atomicAdd(&cursor[dst[gid]], 1);
    col[p] = src[gid];
  }
}

template <int HC, bool ENC>
__global__ void k_gemm_al(const float* __restrict__ hin,
                          const float* __restrict__ encW, const float* __restrict__ encb,
                          const float* __restrict__ W,
                          const float* __restrict__ was, const float* __restrict__ wad,
                          unsigned short* __restrict__ xpb,
                          float* __restrict__ als, float* __restrict__ ald, int N) {
  constexpr int K = 64, NB = 16;
  __shared__ float hs[NB * K];
  int n0 = blockIdx.x * NB;
  int tid = threadIdx.x;
  if (ENC) {
    for (int idx = tid; idx < NB * K; idx += HC) {
      int i = idx >> 6, j = idx & 63;
      int n = n0 + i;
      float a = 0.f;
      if (n < N) {
        a = encb[j];
#pragma unroll
        for (int k = 0; k < 5; ++k) a += hin[n * 5 + k] * encW[k * 64 + j];
      }
      hs[idx] = a;
    }
  } else {
    for (int idx = tid; idx < NB * K; idx += HC) {
      int n = n0 + (idx >> 6);
      hs[idx] = (n < N) ? hin[(size_t)n0 * K + idx] : 0.f;
    }
  }
  __syncthreads();
  float acc[NB];
#pragma unroll
  for (int i = 0; i < NB; ++i) acc[i] = 0.f;
  for (int k = 0; k < K; k += 4) {
    float w0 = W[(k + 0) * HC + tid];
    float w1 = W[(k + 1) * HC + tid];
    float w2 = W[(k + 2) * HC + tid];
    float w3 = W[(k + 3) * HC + tid];
#pragma unroll
    for (int i = 0; i < NB; ++i) {
      float4 hv = *(const float4*)&hs[i * K + k];
      acc[i] += hv.x * w0 + hv.y * w1 + hv.z * w2 + hv.w * w3;
    }
  }
#pragma unroll
  for (int i = 0; i < NB; ++i) {
    int n = n0 + i;
    if (n < N) xpb[(size_t)n * HC + tid] = f2bf(acc[i]);
  }
  if (tid < NB * H4) {
    int i = tid >> 2, h = tid & 3;
    int n = n0 + i;
    float vs = 0.f, vd = 0.f;
#pragma unroll 8
    for (int k = 0; k < K; ++k) {
      float hv = hs[i * K + k];
      vs += hv * was[k * 4 + h];
      vd += hv * wad[k * 4 + h];
    }
    if (n < N) {
      als[n * H4 + h] = vs;
      ald[n * H4 + h] = vd;
    }
  }
}

template <int C, bool RELU, bool POOL>
__global__ __launch_bounds__(128) void k_gather(
    const unsigned short* __restrict__ xpb,
    const float* __restrict__ als, const float* __restrict__ ald,
    const int* __restrict__ rbeg, const int* __restrict__ rend,
    const int* __restrict__ col,
    const float* __restrict__ bias, const float* __restrict__ g,
    const float* __restrict__ be, const float* __restrict__ m,
    const float* __restrict__ v, float* __restrict__ hout,
    float* __restrict__ gpart, int N) {
  constexpr int HC = H4 * C;
  constexpr int VPL = HC / 64;
  __shared__ float accbuf[64 * VPL];
  __shared__ float sbuf[H4];
  int sub = threadIdx.x >> 6;
  int lane = threadIdx.x & 63;
  int n = blockIdx.x;
  int h = lane >> 4;
  float aldn = ald[n * H4 + h];
  int beg = rbeg[n], end = rend[n];
  int len = end - beg;
  int lenA = (len + 1) >> 1;
  int jb = sub ? (beg + lenA) : beg;
  int je = sub ? end : (beg + lenA);

  float s = 0.f;
  float acc[VPL];
#pragma unroll
  for (int i = 0; i < VPL; ++i) acc[i] = 0.f;

  for (int cb = jb; cb < je; cb += 64) {
    int clen = je - cb;
    if (clen > 64) clen = 64;
    int cvec = (lane < clen) ? col[cb + lane] : 0;
    for (int t = 0; t < clen; t += 8) {
      int sv[8];
      float av[8];
#pragma unroll
      for (int i = 0; i < 8; ++i) {
        int idx = t + i;
        sv[i] = __shfl(cvec, (idx < clen) ? idx : 0, 64);
      }
#pragma unroll
      for (int i = 0; i < 8; ++i) av[i] = als[sv[i] * H4 + h];
      if constexpr (VPL == 4) {
        uint2 uv[8];
#pragma unroll
        for (int i = 0; i < 8; ++i)
          uv[i] = *(const uint2*)(xpb + (size_t)sv[i] * HC + lane * 4);
#pragma unroll
        for (int i = 0; i < 8; ++i) {
          float e = (t + i < clen) ? eweight(av[i] + aldn) : 0.f;
          s += e;
          acc[0] += e * bfh(uv[i].x);
          acc[1] += e * bfl(uv[i].x);
          acc[2] += e * bfh(uv[i].y);
          acc[3] += e * bfl(uv[i].y);
        }
      } else {
        unsigned uw[8];
#pragma unroll
        for (int i = 0; i < 8; ++i)
          uw[i] = *(const unsigned*)(xpb + (size_t)sv[i] * HC + lane * 2);
#pragma unroll
        for (int i = 0; i < 8; ++i) {
          float e = (t + i < clen) ? eweight(av[i] + aldn) : 0.f;
          s += e;
          acc[0] += e * bfh(uw[i]);
          acc[1] += e * bfl(uw[i]);
        }
      }
    }
  }

  if (sub) {
    if ((lane & 15) == 0) sbuf[h] = s;
#pragma unroll
    for (int i = 0; i < VPL; ++i) accbuf[lane * VPL + i] = acc[i];
  }
  __syncthreads();
  if (sub) return;
  s += sbuf[h];
#pragma unroll
  for (int i = 0; i < VPL; ++i) acc[i] += accbuf[lane * VPL + i];

  float inv = 1.f / (s + 1e-16f);
#pragma unroll
  for (int i = 0; i < VPL; ++i) {
    acc[i] *= inv;
    acc[i] += __shfl_xor(acc[i], 16, 64);
    acc[i] += __shfl_xor(acc[i], 32, 64);
  }

  if (lane < 16) {
    int c0 = lane * VPL;
    float o[VPL];
#pragma unroll
    for (int i = 0; i < VPL; ++i) {
      int cc = c0 + i;
      float t = acc[i] * (1.f / H4) + bias[cc];
      t = (t - m[cc]) * rsqrtf(v[cc] + 1e-5f) * g[cc] + be[cc];
      if (RELU) t = fmaxf(t, 0.f);
      o[i] = t;
      if (POOL) atomicAdd(&gpart[(blockIdx.x & 255) * 32 + cc], t);
    }
    if constexpr (VPL == 4)
      *(float4*)&hout[(size_t)n * C + c0] = make_float4(o[0], o[1], o[2], o[3]);
    else
      *(float2*)&hout[(size_t)n * C + c0] = make_float2(o[0], o[1]);
  }
}

__global__ void k_heads2(const float* __restrict__ gpart,
                         const float* __restrict__ eW1, const float* __restrict__ eb1,
                         const float* __restrict__ eW2, const float* __restrict__ eb2,
                         const float* __restrict__ mW1, const float* __restrict__ mb1,
                         const float* __restrict__ mW2, const float* __restrict__ mb2,
                         float* __restrict__ out, int N) {
  __shared__ float red[256];
  __shared__ float z[32];
  __shared__ float hid[32];
  int tid = threadIdx.x;
  int c = tid & 31;
  float s = 0.f;
  for (int b = tid >> 5; b < 256; b += 8) s += gpart[b * 32 + c];
  red[tid] = s;
  __syncthreads();
  size_t base = (size_t)N * 32;
  if (tid < 32) {
    float t = 0.f;
#pragma unroll
    for (int i = 0; i < 8; ++i) t += red[i * 32 + tid];
    t /= (float)N;
    z[tid] = t;
    out[base + tid] = t;
  }
  __syncthreads();
  if (tid < 16) {
    float a = eb1[tid], b = mb1[tid];
    for (int k = 0; k < 32; ++k) {
      a += z[k] * eW1[k * 16 + tid];
      b += z[k] * mW1[k * 16 + tid];
    }
    hid[tid] = fmaxf(a, 0.f);
    hid[16 + tid] = fmaxf(b, 0.f);
  }
  __syncthreads();
  if (tid == 0) {
    float a = eb2[0];
    for (int k = 0; k < 16; ++k) a += hid[k] * eW2[k];
    out[base + 32] = 1.f / (1.f + __expf(-a));
  } else if (tid == 1) {
    float a = mb2[0];
    for (int k = 0; k < 16; ++k) a += hid[16 + k] * mW2[k];
    out[base + 33] = 1.f / (1.f + __expf(-a));
  }
}

extern "C" void kernel_launch(void* const* d_in, const int* in_sizes, int n_in,
                              void* d_out, int out_size, void* d_ws, size_t ws_size,
                              hipStream_t stream) {
  const int N = in_sizes[0] / 5;   // x is (N,5)
  const int E = in_sizes[1] / 2;   // edge_index is (2,E)
  const int M = E + N;             // CSR slots incl. self-loops

  MegaParams P;
  P.x = (const float*)d_in[0];
  const int* ei = (const int*)d_in[1];
  P.e_src = ei;
  P.e_dst = ei + E;
  P.encW = (const float*)d_in[2];
  P.encb = (const float*)d_in[3];
  for (int l = 0; l < 3; ++l) {
    const int o = 4 + 8 * l;
    P.W[l]   = (const float*)d_in[o + 0];
    P.as_[l] = (const float*)d_in[o + 1];
    P.ad_[l] = (const float*)d_in[o + 2];
    P.b_[l]  = (const float*)d_in[o + 3];
    P.g_[l]  = (const float*)d_in[o + 4];
    P.be_[l] = (const float*)d_in[o + 5];
    P.m_[l]  = (const float*)d_in[o + 6];
    P.v_[l]  = (const float*)d_in[o + 7];
  }
  P.eW1 = (const float*)d_in[28]; P.eb1 = (const float*)d_in[29];
  P.eW2 = (const float*)d_in[30]; P.eb2 = (const float*)d_in[31];
  P.mW1 = (const float*)d_in[32]; P.mb1 = (const float*)d_in[33];
  P.mW2 = (const float*)d_in[34]; P.mb2 = (const float*)d_in[35];
  P.out = (float*)d_out;
  P.N = N; P.E = E;

  // workspace layout: floats, then int region, then gpart, then barrier state
  float* wf = (float*)d_ws;
  size_t off = 0;
  P.hA = wf + off; off += (size_t)N * 64;
  P.hB = wf + off; off += (size_t)N * 64;
  P.xpb = (unsigned short*)(wf + off); off += (size_t)N * 128;  // N*256 bf16
  P.als = wf + off; off += (size_t)N * 4;
  P.ald = wf + off; off += (size_t)N * 4;
  P.pas = wf + off; off += 3 * 256;
  P.pad = wf + off; off += 3 * 256;
  int* wi = (int*)(wf + off);
  P.col = wi;                        // M
  P.rbeg = P.col + M;                // N
  P.rend = P.rbeg + N;               // N
  P.cursor = P.rend + N;             // N   } contiguous: zeroed in-kernel (mega)
  P.counter = P.cursor + N;          // 1   } or by memset (legacy)
  P.gpart = (float*)(P.counter + 1); // 256*32
  {
    uintptr_t ba = (uintptr_t)(P.gpart + 256 * 32);
    ba = (ba + 7) & ~(uintptr_t)7;   // 8-align for the u64 magic
    P.bar = (int*)ba;                // [0:2): ready magic, [2]: barrier counter
  }

  // ---- try the persistent mega-kernel (custom barrier), sized & checked ----
  bool done = false;
  {
    int dev = 0;
    if (hipGetDevice(&dev) == hipSuccess) {
      int numCU = 0, maxPerCU = 0;
      if (hipDeviceGetAttribute(&numCU, hipDeviceAttributeMultiprocessorCount, dev) == hipSuccess &&
          hipOccupancyMaxActiveBlocksPerMultiprocessor(&maxPerCU, (const void*)k_mega, NTHR, 0) == hipSuccess &&
          numCU > 0 && maxPerCU > 0) {
        long nblk = (long)maxPerCU * numCU;
        if (nblk > 2048) nblk = 2048;
        void* args[] = {(void*)&P};
        if (hipLaunchCooperativeKernel((void*)k_mega, dim3((unsigned)nblk), dim3(NTHR),
                                       args, 0, stream) == hipSuccess)
          done = true;
      }
    }
  }
  if (done) return;

  // ---- legacy fallback: proven R9 11-dispatch path ----
  const int T = 256;
  const int gE  = (E + T - 1) / T;
  const int gN  = (N + T - 1) / T;
  const int gGE = (N + 15) / 16;

  hipMemsetAsync(P.cursor, 0, (size_t)(N + 1) * sizeof(int) + 256 * 32 * sizeof(float), stream);
  k_count<<<gE, T, 0, stream>>>(P.e_dst, P.cursor, E);
  k_alloc<<<gN, T, 0, stream>>>(P.cursor, P.rbeg, P.rend, P.col, P.counter, N,
                                P.W[0], P.as_[0], P.ad_[0], P.W[1], P.as_[1], P.ad_[1],
                                P.W[2], P.as_[2], P.ad_[2], P.pas, P.pad);
  k_scatter<<<gE, T, 0, stream>>>(P.e_src, P.e_dst, P.cursor, P.col, E);

  k_gemm_al<256, true><<<gGE, 256, 0, stream>>>(P.x, P.encW, P.encb, P.W[0], P.pas, P.pad,
                                                P.xpb, P.als, P.ald, N);
  k_gather<64, true, false><<<N, 128, 0, stream>>>(P.xpb, P.als, P.ald, P.rbeg, P.rend, P.col,
                                                   P.b_[0], P.g_[0], P.be_[0], P.m_[0], P.v_[0],
                                                   P.hB, P.gpart, N);

  k_gemm_al<256, false><<<gGE, 256, 0, stream>>>(P.hB, P.encW, P.encb, P.W[1], P.pas + 256, P.pad + 256,
                                                 P.xpb, P.als, P.ald, N);
  k_gather<64, true, false><<<N, 128, 0, stream>>>(P.xpb, P.als, P.ald, P.rbeg, P.rend, P.col,
                                                   P.b_[1], P.g_[1], P.be_[1], P.m_[1], P.v_[1],
                                                   P.hA, P.gpart, N);

  k_gemm_al<128, false><<<gGE, 128, 0, stream>>>(P.hA, P.encW, P.encb, P.W[2], P.pas + 512, P.pad + 512,
                                                 P.xpb, P.als, P.ald, N);
  k_gather<32, false, true><<<N, 128, 0, stream>>>(P.xpb, P.als, P.ald, P.rbeg, P.rend, P.col,
                                                   P.b_[2], P.g_[2], P.be_[2], P.m_[2], P.v_[2],
                                                   P.out, P.gpart, N);

  k_heads2<<<1, 256, 0, stream>>>(P.gpart, P.eW1, P.eb1, P.eW2, P.eb2,
                                  P.mW1, P.mb1, P.mW2, P.mb2, P.out, N);
}

// Round 7
// 671.369 us; speedup vs baseline: 2.4037x; 1.4505x over previous
//
#include <hip/hip_runtime.h>
#include <math.h>

// EthicalGNN: encoder -> 3x(GAT + BN (+ReLU)) -> mean-pool -> 2 MLP heads.
// R14: persistent mega-kernel with a TREE grid barrier. R13's single-counter
// barrier cost ~125us/sync at G=2048: 2048 serialized RMWs on one line plus
// 2048 spinners hammering the same line (s_sleep(2)=128cyc) saturating that
// LLC bank. Here: arrival on 64 padded counters (32-way RMW each, parallel
// across lines), one root add per group-finisher (64 adds), release via
// per-group go flags (spinners spread over 64 lines, s_sleep(8)). Phase
// bodies byte-identical to R12/R13 (twice-PASSED). Grid forced to a multiple
// of 64; proven R9 11-dispatch fallback if coop launch unavailable.

#define H4 4  // heads
#define NTHR 256
#define BAR_MAGIC 0x9E3779B97F4A7C15ULL

static __device__ __forceinline__ unsigned short f2bf(float f) {
  unsigned u = __float_as_uint(f);
  u += 0x7fffu + ((u >> 16) & 1u);  // round-to-nearest-even
  return (unsigned short)(u >> 16);
}
static __device__ __forceinline__ float bfh(unsigned u) {  // low bf16 -> f32
  return __uint_as_float(u << 16);
}
static __device__ __forceinline__ float bfl(unsigned u) {  // high bf16 -> f32
  return __uint_as_float(u & 0xffff0000u);
}
static __device__ __forceinline__ float eweight(float a) {
  a = (a > 0.f) ? a : 0.2f * a;  // leaky_relu 0.2
  return __expf(a);
}

// Barrier state layout (ints, 64B-line padded):
//   [0]          root counter          (line 0)
//   [16 + g*16]  arr[g]  g=0..63      (lines 1..64)
//   [1040 + g*16] go[g]  g=0..63      (lines 65..128)
//   [2064..2065] ready magic (u64)    (line 129)
#define BAR_ROOT 0
#define BAR_ARR(g) (16 + ((g) << 4))
#define BAR_GO(g) (1040 + ((g) << 4))
#define BAR_MAGIC_OFF 2064
#define BAR_INTS 2080

// Tree grid barrier, monotonic (no resets). Call k waits for all G blocks.
// G must be a multiple of 64. ng = G/64 blocks per arrival group.
static __device__ __forceinline__ void gbar(int* bar, unsigned gen, int ng) {
  __syncthreads();
  if (threadIdx.x == 0) {
    int g = blockIdx.x & 63;
    __threadfence();  // release: my block's writes -> device visible
    unsigned old = atomicAdd((unsigned*)&bar[BAR_ARR(g)], 1u);
    if (old == gen * (unsigned)ng - 1u) {
      // last arriver of this group: bump root, wait all groups, release group
      atomicAdd((unsigned*)&bar[BAR_ROOT], 1u);
      while ((unsigned)__hip_atomic_load(&bar[BAR_ROOT], __ATOMIC_RELAXED,
                                         __HIP_MEMORY_SCOPE_AGENT) < gen * 64u)
        __builtin_amdgcn_s_sleep(8);
      __hip_atomic_store(&bar[BAR_GO(g)], (int)gen, __ATOMIC_RELAXED,
                         __HIP_MEMORY_SCOPE_AGENT);
    } else {
      while ((unsigned)__hip_atomic_load(&bar[BAR_GO(g)], __ATOMIC_RELAXED,
                                         __HIP_MEMORY_SCOPE_AGENT) < gen)
        __builtin_amdgcn_s_sleep(8);
    }
    __threadfence();  // acquire: see other blocks' writes
  }
  __syncthreads();
}

struct MegaParams {
  const float* x; const int* e_src; const int* e_dst;
  const float* encW; const float* encb;
  const float* W[3]; const float* as_[3]; const float* ad_[3];
  const float* b_[3]; const float* g_[3]; const float* be_[3];
  const float* m_[3]; const float* v_[3];
  const float* eW1; const float* eb1; const float* eW2; const float* eb2;
  const float* mW1; const float* mb1; const float* mW2; const float* mb2;
  float* out; float* hA; float* hB; unsigned short* xpb;
  float* als; float* ald; float* pas; float* pad;
  int* col; int* rbeg; int* rend; int* cursor; int* counter; float* gpart;
  int* bar;
  int N; int E;
};

// ---------------- mega: fused GEMM + attention logits (block-stride) ---------
template <int HC, bool ENC>
static __device__ void gemm_phase(const float* __restrict__ hin,
                                  const float* __restrict__ encW,
                                  const float* __restrict__ encb,
                                  const float* __restrict__ W,
                                  const float* __restrict__ was,
                                  const float* __restrict__ wad,
                                  unsigned short* __restrict__ xpb,
                                  float* __restrict__ als, float* __restrict__ ald,
                                  int N, float* hs, int bid) {
  constexpr int K = 64, NB = 16;
  int tid = threadIdx.x;
  int G = gridDim.x;
  if constexpr (HC == 256) {
    int ntiles = (N + NB - 1) / NB;
    for (int tix = bid; tix < ntiles; tix += G) {
      int n0 = tix * NB;
      for (int idx = tid; idx < NB * K; idx += NTHR) {
        int i = idx >> 6, j = idx & 63;
        int n = n0 + i;
        float a = 0.f;
        if constexpr (ENC) {
          if (n < N) {
            a = encb[j];
#pragma unroll
            for (int k = 0; k < 5; ++k) a += hin[n * 5 + k] * encW[k * 64 + j];
          }
        } else {
          a = (n < N) ? hin[(size_t)n0 * K + idx] : 0.f;
        }
        hs[idx] = a;
      }
      __syncthreads();
      float acc[NB];
#pragma unroll
      for (int i = 0; i < NB; ++i) acc[i] = 0.f;
      for (int k = 0; k < K; k += 4) {
        float w0 = W[(k + 0) * HC + tid];
        float w1 = W[(k + 1) * HC + tid];
        float w2 = W[(k + 2) * HC + tid];
        float w3 = W[(k + 3) * HC + tid];
#pragma unroll
        for (int i = 0; i < NB; ++i) {
          float4 hv = *(const float4*)&hs[i * K + k];
          acc[i] += hv.x * w0 + hv.y * w1 + hv.z * w2 + hv.w * w3;
        }
      }
#pragma unroll
      for (int i = 0; i < NB; ++i) {
        int n = n0 + i;
        if (n < N) xpb[(size_t)n * HC + tid] = f2bf(acc[i]);
      }
      if (tid < NB * H4) {
        int i = tid >> 2, h = tid & 3;
        int n = n0 + i;
        float vs = 0.f, vd = 0.f;
#pragma unroll 8
        for (int k = 0; k < K; ++k) {
          float hv = hs[i * K + k];
          vs += hv * was[k * 4 + h];
          vd += hv * wad[k * 4 + h];
        }
        if (n < N) { als[n * H4 + h] = vs; ald[n * H4 + h] = vd; }
      }
      __syncthreads();
    }
  } else {  // HC == 128: dual 16-node subtiles per 256-thr block
    int sub = tid >> 7, t2 = tid & 127;
    int ntiles = (N + 31) / 32;
    for (int tix = bid; tix < ntiles; tix += G) {
      int n0 = tix * 32;
      for (int idx = tid; idx < 32 * K; idx += NTHR) {
        int n = n0 + (idx >> 6);
        hs[idx] = (n < N) ? hin[(size_t)n0 * K + idx] : 0.f;
      }
      __syncthreads();
      int nb0 = n0 + sub * NB;
      const float* hsub = hs + sub * NB * K;
      float acc[NB];
#pragma unroll
      for (int i = 0; i < NB; ++i) acc[i] = 0.f;
      for (int k = 0; k < K; k += 4) {
        float w0 = W[(k + 0) * HC + t2];
        float w1 = W[(k + 1) * HC + t2];
        float w2 = W[(k + 2) * HC + t2];
        float w3 = W[(k + 3) * HC + t2];
#pragma unroll
        for (int i = 0; i < NB; ++i) {
          float4 hv = *(const float4*)&hsub[i * K + k];
          acc[i] += hv.x * w0 + hv.y * w1 + hv.z * w2 + hv.w * w3;
        }
      }
#pragma unroll
      for (int i = 0; i < NB; ++i) {
        int n = nb0 + i;
        if (n < N) xpb[(size_t)n * HC + t2] = f2bf(acc[i]);
      }
      if (t2 < NB * H4) {
        int i = t2 >> 2, h = t2 & 3;
        int n = nb0 + i;
        float vs = 0.f, vd = 0.f;
#pragma unroll 8
        for (int k = 0; k < K; ++k) {
          float hv = hsub[i * K + k];
          vs += hv * was[k * 4 + h];
          vd += hv * wad[k * 4 + h];
        }
        if (n < N) { als[n * H4 + h] = vs; ald[n * H4 + h] = vd; }
      }
      __syncthreads();
    }
  }
}

// ---------------- mega: gather phase (2 waves/node, 2 nodes/block-iter) ------
template <int C, bool RELU, bool POOL>
static __device__ void gather_phase(const unsigned short* __restrict__ xpb,
                                    const float* __restrict__ als,
                                    const float* __restrict__ ald,
                                    const int* __restrict__ rbeg,
                                    const int* __restrict__ rend,
                                    const int* __restrict__ col,
                                    const float* __restrict__ bias,
                                    const float* __restrict__ g,
                                    const float* __restrict__ be,
                                    const float* __restrict__ m,
                                    const float* __restrict__ v,
                                    float* __restrict__ hout,
                                    float* __restrict__ gpart,
                                    int N, float* smem, int bid) {
  constexpr int HC = H4 * C;
  constexpr int VPL = HC / 64;  // 4 (C=64) or 2 (C=32)
  float* accbuf = smem;               // 2 groups * 64*VPL
  float* sbuf = smem + 2 * 64 * VPL;  // 2 groups * 4
  int wid = threadIdx.x >> 6;
  int grp = wid >> 1, sub = wid & 1;
  int lane = threadIdx.x & 63;
  int h = lane >> 4;
  int G = gridDim.x;
  int niter = (N + 2 * G - 1) / (2 * G);
  for (int it = 0; it < niter; ++it) {
    int n = it * (2 * G) + bid * 2 + grp;
    bool valid = (n < N);
    float s = 0.f;
    float acc[VPL];
#pragma unroll
    for (int i = 0; i < VPL; ++i) acc[i] = 0.f;
    float aldn = 0.f;
    int jb = 0, je = 0;
    if (valid) {
      aldn = ald[n * H4 + h];
      int beg = rbeg[n], end = rend[n];
      int len = end - beg;
      int lenA = (len + 1) >> 1;
      jb = sub ? (beg + lenA) : beg;
      je = sub ? end : (beg + lenA);
    }
    for (int cb = jb; cb < je; cb += 64) {
      int clen = je - cb;
      if (clen > 64) clen = 64;
      int cvec = (lane < clen) ? col[cb + lane] : 0;  // one coalesced load
      for (int t = 0; t < clen; t += 8) {
        int sv[8];
        float av[8];
#pragma unroll
        for (int i = 0; i < 8; ++i) {
          int idx = t + i;
          sv[i] = __shfl(cvec, (idx < clen) ? idx : 0, 64);
        }
#pragma unroll
        for (int i = 0; i < 8; ++i) av[i] = als[sv[i] * H4 + h];
        if constexpr (VPL == 4) {
          uint2 uv[8];
#pragma unroll
          for (int i = 0; i < 8; ++i)
            uv[i] = *(const uint2*)(xpb + (size_t)sv[i] * HC + lane * 4);
#pragma unroll
          for (int i = 0; i < 8; ++i) {
            float e = (t + i < clen) ? eweight(av[i] + aldn) : 0.f;
            s += e;
            acc[0] += e * bfh(uv[i].x);
            acc[1] += e * bfl(uv[i].x);
            acc[2] += e * bfh(uv[i].y);
            acc[3] += e * bfl(uv[i].y);
          }
        } else {
          unsigned uw[8];
#pragma unroll
          for (int i = 0; i < 8; ++i)
            uw[i] = *(const unsigned*)(xpb + (size_t)sv[i] * HC + lane * 2);
#pragma unroll
          for (int i = 0; i < 8; ++i) {
            float e = (t + i < clen) ? eweight(av[i] + aldn) : 0.f;
            s += e;
            acc[0] += e * bfh(uw[i]);
            acc[1] += e * bfl(uw[i]);
          }
        }
      }
    }
    if (valid && sub) {
      if ((lane & 15) == 0) sbuf[grp * 4 + h] = s;
#pragma unroll
      for (int i = 0; i < VPL; ++i) accbuf[grp * 64 * VPL + lane * VPL + i] = acc[i];
    }
    __syncthreads();
    if (valid && !sub) {
      s += sbuf[grp * 4 + h];
#pragma unroll
      for (int i = 0; i < VPL; ++i) acc[i] += accbuf[grp * 64 * VPL + lane * VPL + i];
      float inv = 1.f / (s + 1e-16f);
#pragma unroll
      for (int i = 0; i < VPL; ++i) {
        acc[i] *= inv;
        acc[i] += __shfl_xor(acc[i], 16, 64);  // head sum (bits 4,5 = head)
        acc[i] += __shfl_xor(acc[i], 32, 64);
      }
      if (lane < 16) {
        int c0 = lane * VPL;
        float o[VPL];
#pragma unroll
        for (int i = 0; i < VPL; ++i) {
          int cc = c0 + i;
          float t = acc[i] * (1.f / H4) + bias[cc];
          t = (t - m[cc]) * rsqrtf(v[cc] + 1e-5f) * g[cc] + be[cc];
          if (RELU) t = fmaxf(t, 0.f);
          o[i] = t;
          if (POOL) atomicAdd(&gpart[(n & 255) * 32 + cc], t);
        }
        if constexpr (VPL == 4)
          *(float4*)&hout[(size_t)n * C + c0] = make_float4(o[0], o[1], o[2], o[3]);
        else
          *(float2*)&hout[(size_t)n * C + c0] = make_float2(o[0], o[1]);
      }
    }
    __syncthreads();
  }
}

// ---------------- mega: heads (block 0 only) ---------------------------------
static __device__ void heads_phase(const MegaParams& P, float* smem) {
  float* red = smem;        // 256
  float* z = smem + 256;    // 32
  float* hid = smem + 288;  // 32
  int tid = threadIdx.x;
  int c = tid & 31;
  float s = 0.f;
  for (int b = tid >> 5; b < 256; b += 8) s += P.gpart[b * 32 + c];
  red[tid] = s;
  __syncthreads();
  size_t base = (size_t)P.N * 32;
  if (tid < 32) {
    float t = 0.f;
#pragma unroll
    for (int i = 0; i < 8; ++i) t += red[i * 32 + tid];
    t /= (float)P.N;
    z[tid] = t;
    P.out[base + tid] = t;  // graph_emb
  }
  __syncthreads();
  if (tid < 16) {
    float a = P.eb1[tid], b = P.mb1[tid];
    for (int k = 0; k < 32; ++k) {
      a += z[k] * P.eW1[k * 16 + tid];
      b += z[k] * P.mW1[k * 16 + tid];
    }
    hid[tid] = fmaxf(a, 0.f);
    hid[16 + tid] = fmaxf(b, 0.f);
  }
  __syncthreads();
  if (tid == 0) {
    float a = P.eb2[0];
    for (int k = 0; k < 16; ++k) a += hid[k] * P.eW2[k];
    P.out[base + 32] = 1.f / (1.f + __expf(-a));
  } else if (tid == 1) {
    float a = P.mb2[0];
    for (int k = 0; k < 16; ++k) a += hid[16 + k] * P.mW2[k];
    P.out[base + 33] = 1.f / (1.f + __expf(-a));
  }
}

// ---------------- the mega-kernel --------------------------------------------
__global__ __launch_bounds__(NTHR, 4) void k_mega(MegaParams P) {
  __shared__ float smem[2048];  // 8 KB
  const int tid = threadIdx.x, bid = blockIdx.x;
  const int G = gridDim.x;
  const int gstr = G * NTHR;
  const int ng = G >> 6;  // blocks per arrival group (G is a multiple of 64)
  unsigned long long* readyp = (unsigned long long*)&P.bar[BAR_MAGIC_OFF];
  unsigned bgen = 0;

  // Init handshake: workspace is poisoned each replay; block 0 zeroes the
  // barrier state and publishes MAGIC; all blocks wait for MAGIC.
  if (bid == 0) {
    for (int i = tid; i < BAR_MAGIC_OFF; i += NTHR) P.bar[i] = 0;
    __syncthreads();
    if (tid == 0) {
      __threadfence();
      __hip_atomic_store(readyp, BAR_MAGIC, __ATOMIC_RELAXED, __HIP_MEMORY_SCOPE_AGENT);
    }
  }
  if (tid == 0) {
    while (__hip_atomic_load(readyp, __ATOMIC_RELAXED, __HIP_MEMORY_SCOPE_AGENT) != BAR_MAGIC)
      __builtin_amdgcn_s_sleep(8);
    __threadfence();
  }
  __syncthreads();

#define GSYNC() gbar(P.bar, ++bgen, ng)

  // P0: zero cursor + counter + gpart (contiguous)
  {
    int zn = P.N + 1 + 256 * 32;
    for (int i = bid * NTHR + tid; i < zn; i += gstr) P.cursor[i] = 0;
  }
  GSYNC();

  // P1: degree count
  for (int i = bid * NTHR + tid; i < P.E; i += gstr)
    atomicAdd(&P.cursor[P.e_dst[i]], 1);
  GSYNC();

  // P2: region alloc (wave scan + one atomic per 64-node chunk) + was/wad prep
  {
    int lane = tid & 63, wid = tid >> 6;
    int nch = (P.N + 63) >> 6;
    for (int ch = bid * 4 + wid; ch < nch; ch += G * 4) {
      int gid = ch * 64 + lane;
      int size = (gid < P.N) ? (P.cursor[gid] + 1) : 0;  // +1 self-loop
      int v = size;
#pragma unroll
      for (int off = 1; off < 64; off <<= 1) {
        int t = __shfl_up(v, off, 64);
        if (lane >= off) v += t;
      }
      int tot = __shfl(v, 63, 64);
      int base = 0;
      if (lane == 63) base = atomicAdd(P.counter, tot);
      base = __shfl(base, 63, 64);
      if (gid < P.N) {
        int p = base + v - size;  // exclusive prefix
        P.rbeg[gid] = p;
        P.rend[gid] = p + size;
        P.col[p] = gid;  // self-loop slot
        P.cursor[gid] = p + 1;
      }
    }
    if (bid < 3) {  // was/wad[k,h] = sum_c W[k,h*C+c]*a[h,c]
      int l = bid;
      const float* W = P.W[l];
      const float* ap = P.as_[l];
      const float* dp = P.ad_[l];
      int HC = (l == 2) ? 128 : 256;
      int C = HC / H4;
      int k = tid >> 2, h = tid & 3;
      float vs = 0.f, vd = 0.f;
      for (int c = 0; c < C; ++c) {
        float w = W[k * HC + h * C + c];
        vs += w * ap[h * C + c];
        vd += w * dp[h * C + c];
      }
      P.pas[l * 256 + tid] = vs;
      P.pad[l * 256 + tid] = vd;
    }
  }
  GSYNC();

  // P3: scatter (col) + gemm0 (independent of CSR)
  for (int i = bid * NTHR + tid; i < P.E; i += gstr) {
    int p = atomicAdd(&P.cursor[P.e_dst[i]], 1);
    P.col[p] = P.e_src[i];
  }
  gemm_phase<256, true>(P.x, P.encW, P.encb, P.W[0], P.pas, P.pad,
                        P.xpb, P.als, P.ald, P.N, smem, bid);
  GSYNC();

  gather_phase<64, true, false>(P.xpb, P.als, P.ald, P.rbeg, P.rend, P.col,
                                P.b_[0], P.g_[0], P.be_[0], P.m_[0], P.v_[0],
                                P.hB, P.gpart, P.N, smem, bid);
  GSYNC();

  gemm_phase<256, false>(P.hB, nullptr, nullptr, P.W[1], P.pas + 256, P.pad + 256,
                         P.xpb, P.als, P.ald, P.N, smem, bid);
  GSYNC();

  gather_phase<64, true, false>(P.xpb, P.als, P.ald, P.rbeg, P.rend, P.col,
                                P.b_[1], P.g_[1], P.be_[1], P.m_[1], P.v_[1],
                                P.hA, P.gpart, P.N, smem, bid);
  GSYNC();

  gemm_phase<128, false>(P.hA, nullptr, nullptr, P.W[2], P.pas + 512, P.pad + 512,
                         P.xpb, P.als, P.ald, P.N, smem, bid);
  GSYNC();

  gather_phase<32, false, true>(P.xpb, P.als, P.ald, P.rbeg, P.rend, P.col,
                                P.b_[2], P.g_[2], P.be_[2], P.m_[2], P.v_[2],
                                P.out, P.gpart, P.N, smem, bid);
  GSYNC();

  if (bid == 0) heads_phase(P, smem);
#undef GSYNC
}

// ======================= legacy fallback (R9, proven) ========================
__global__ void k_count(const int* __restrict__ dst, int* __restrict__ deg, int E) {
  int gid = blockIdx.x * blockDim.x + threadIdx.x;
  if (gid < E) atomicAdd(&deg[dst[gid]], 1);
}

__global__ void k_alloc(int* __restrict__ cursor, int* __restrict__ rbeg,
                        int* __restrict__ rend, int* __restrict__ col,
                        int* __restrict__ counter, int N,
                        const float* __restrict__ W0, const float* __restrict__ as0, const float* __restrict__ ad0,
                        const float* __restrict__ W1, const float* __restrict__ as1, const float* __restrict__ ad1,
                        const float* __restrict__ W2, const float* __restrict__ as2, const float* __restrict__ ad2,
                        float* __restrict__ pas, float* __restrict__ pad) {
  int gid = blockIdx.x * blockDim.x + threadIdx.x;
  int lane = threadIdx.x & 63;
  int size = (gid < N) ? (cursor[gid] + 1) : 0;
  int v = size;
#pragma unroll
  for (int off = 1; off < 64; off <<= 1) {
    int t = __shfl_up(v, off, 64);
    if (lane >= off) v += t;
  }
  int tot = __shfl(v, 63, 64);
  int base = 0;
  if (lane == 63) base = atomicAdd(counter, tot);
  base = __shfl(base, 63, 64);
  if (gid < N) {
    int p = base + v - size;
    rbeg[gid] = p;
    rend[gid] = p + size;
    col[p] = gid;
    cursor[gid] = p + 1;
  }
  if (blockIdx.x < 3) {
    int l = blockIdx.x;
    const float* W  = (l == 0) ? W0 : (l == 1) ? W1 : W2;
    const float* ap = (l == 0) ? as0 : (l == 1) ? as1 : as2;
    const float* dp = (l == 0) ? ad0 : (l == 1) ? ad1 : ad2;
    int HC = (l == 2) ? 128 : 256;
    int C  = HC / H4;
    int tid = threadIdx.x;
    int k = tid >> 2, h = tid & 3;
    float vs = 0.f, vd = 0.f;
    for (int c = 0; c < C; ++c) {
      float w = W[k * HC + h * C + c];
      vs += w * ap[h * C + c];
      vd += w * dp[h * C + c];
    }
    pas[l * 256 + tid] = vs;
    pad[l * 256 + tid] = vd;
  }
}

__global__ void k_scatter(const int* __restrict__ src, const int* __restrict__ dst,
                          int* __restrict__ cursor, int* __restrict__ col, int E) {
  int gid = blockIdx.x * blockDim.x + threadIdx.x;
  if (gid < E) {
    int p = atomicAdd(&cursor[dst[gid]], 1);
    col[p] = src[gid];
  }
}

template <int HC, bool ENC>
__global__ void k_gemm_al(const float* __restrict__ hin,
                          const float* __restrict__ encW, const float* __restrict__ encb,
                          const float* __restrict__ W,
                          const float* __restrict__ was, const float* __restrict__ wad,
                          unsigned short* __restrict__ xpb,
                          float* __restrict__ als, float* __restrict__ ald, int N) {
  constexpr int K = 64, NB = 16;
  __shared__ float hs[NB * K];
  int n0 = blockIdx.x * NB;
  int tid = threadIdx.x;
  if (ENC) {
    for (int idx = tid; idx < NB * K; idx += HC) {
      int i = idx >> 6, j = idx & 63;
      int n = n0 + i;
      float a = 0.f;
      if (n < N) {
        a = encb[j];
#pragma unroll
        for (int k = 0; k < 5; ++k) a += hin[n * 5 + k] * encW[k * 64 + j];
      }
      hs[idx] = a;
    }
  } else {
    for (int idx = tid; idx < NB * K; idx += HC) {
      int n = n0 + (idx >> 6);
      hs[idx] = (n < N) ? hin[(size_t)n0 * K + idx] : 0.f;
    }
  }
  __syncthreads();
  float acc[NB];
#pragma unroll
  for (int i = 0; i < NB; ++i) acc[i] = 0.f;
  for (int k = 0; k < K; k += 4) {
    float w0 = W[(k + 0) * HC + tid];
    float w1 = W[(k + 1) * HC + tid];
    float w2 = W[(k + 2) * HC + tid];
    float w3 = W[(k + 3) * HC + tid];
#pragma unroll
    for (int i = 0; i < NB; ++i) {
      float4 hv = *(const float4*)&hs[i * K + k];
      acc[i] += hv.x * w0 + hv.y * w1 + hv.z * w2 + hv.w * w3;
    }
  }
#pragma unroll
  for (int i = 0; i < NB; ++i) {
    int n = n0 + i;
    if (n < N) xpb[(size_t)n * HC + tid] = f2bf(acc[i]);
  }
  if (tid < NB * H4) {
    int i = tid >> 2, h = tid & 3;
    int n = n0 + i;
    float vs = 0.f, vd = 0.f;
#pragma unroll 8
    for (int k = 0; k < K; ++k) {
      float hv = hs[i * K + k];
      vs += hv * was[k * 4 + h];
      vd += hv * wad[k * 4 + h];
    }
    if (n < N) {
      als[n * H4 + h] = vs;
      ald[n * H4 + h] = vd;
    }
  }
}

template <int C, bool RELU, bool POOL>
__global__ __launch_bounds__(128) void k_gather(
    const unsigned short* __restrict__ xpb,
    const float* __restrict__ als, const float* __restrict__ ald,
    const int* __restrict__ rbeg, const int* __restrict__ rend,
    const int* __restrict__ col,
    const float* __restrict__ bias, const float* __restrict__ g,
    const float* __restrict__ be, const float* __restrict__ m,
    const float* __restrict__ v, float* __restrict__ hout,
    float* __restrict__ gpart, int N) {
  constexpr int HC = H4 * C;
  constexpr int VPL = HC / 64;
  __shared__ float accbuf[64 * VPL];
  __shared__ float sbuf[H4];
  int sub = threadIdx.x >> 6;
  int lane = threadIdx.x & 63;
  int n = blockIdx.x;
  int h = lane >> 4;
  float aldn = ald[n * H4 + h];
  int beg = rbeg[n], end = rend[n];
  int len = end - beg;
  int lenA = (len + 1) >> 1;
  int jb = sub ? (beg + lenA) : beg;
  int je = sub ? end : (beg + lenA);

  float s = 0.f;
  float acc[VPL];
#pragma unroll
  for (int i = 0; i < VPL; ++i) acc[i] = 0.f;

  for (int cb = jb; cb < je; cb += 64) {
    int clen = je - cb;
    if (clen > 64) clen = 64;
    int cvec = (lane < clen) ? col[cb + lane] : 0;
    for (int t = 0; t < clen; t += 8) {
      int sv[8];
      float av[8];
#pragma unroll
      for (int i = 0; i < 8; ++i) {
        int idx = t + i;
        sv[i] = __shfl(cvec, (idx < clen) ? idx : 0, 64);
      }
#pragma unroll
      for (int i = 0; i < 8; ++i) av[i] = als[sv[i] * H4 + h];
      if constexpr (VPL == 4) {
        uint2 uv[8];
#pragma unroll
        for (int i = 0; i < 8; ++i)
          uv[i] = *(const uint2*)(xpb + (size_t)sv[i] * HC + lane * 4);
#pragma unroll
        for (int i = 0; i < 8; ++i) {
          float e = (t + i < clen) ? eweight(av[i] + aldn) : 0.f;
          s += e;
          acc[0] += e * bfh(uv[i].x);
          acc[1] += e * bfl(uv[i].x);
          acc[2] += e * bfh(uv[i].y);
          acc[3] += e * bfl(uv[i].y);
        }
      } else {
        unsigned uw[8];
#pragma unroll
        for (int i = 0; i < 8; ++i)
          uw[i] = *(const unsigned*)(xpb + (size_t)sv[i] * HC + lane * 2);
#pragma unroll
        for (int i = 0; i < 8; ++i) {
          float e = (t + i < clen) ? eweight(av[i] + aldn) : 0.f;
          s += e;
          acc[0] += e * bfh(uw[i]);
          acc[1] += e * bfl(uw[i]);
        }
      }
    }
  }

  if (sub) {
    if ((lane & 15) == 0) sbuf[h] = s;
#pragma unroll
    for (int i = 0; i < VPL; ++i) accbuf[lane * VPL + i] = acc[i];
  }
  __syncthreads();
  if (sub) return;
  s += sbuf[h];
#pragma unroll
  for (int i = 0; i < VPL; ++i) acc[i] += accbuf[lane * VPL + i];

  float inv = 1.f / (s + 1e-16f);
#pragma unroll
  for (int i = 0; i < VPL; ++i) {
    acc[i] *= inv;
    acc[i] += __shfl_xor(acc[i], 16, 64);
    acc[i] += __shfl_xor(acc[i], 32, 64);
  }

  if (lane < 16) {
    int c0 = lane * VPL;
    float o[VPL];
#pragma unroll
    for (int i = 0; i < VPL; ++i) {
      int cc = c0 + i;
      float t = acc[i] * (1.f / H4) + bias[cc];
      t = (t - m[cc]) * rsqrtf(v[cc] + 1e-5f) * g[cc] + be[cc];
      if (RELU) t = fmaxf(t, 0.f);
      o[i] = t;
      if (POOL) atomicAdd(&gpart[(blockIdx.x & 255) * 32 + cc], t);
    }
    if constexpr (VPL == 4)
      *(float4*)&hout[(size_t)n * C + c0] = make_float4(o[0], o[1], o[2], o[3]);
    else
      *(float2*)&hout[(size_t)n * C + c0] = make_float2(o[0], o[1]);
  }
}

__global__ void k_heads2(const float* __restrict__ gpart,
                         const float* __restrict__ eW1, const float* __restrict__ eb1,
                         const float* __restrict__ eW2, const float* __restrict__ eb2,
                         const float* __restrict__ mW1, const float* __restrict__ mb1,
                         const float* __restrict__ mW2, const float* __restrict__ mb2,
                         float* __restrict__ out, int N) {
  __shared__ float red[256];
  __shared__ float z[32];
  __shared__ float hid[32];
  int tid = threadIdx.x;
  int c = tid & 31;
  float s = 0.f;
  for (int b = tid >> 5; b < 256; b += 8) s += gpart[b * 32 + c];
  red[tid] = s;
  __syncthreads();
  size_t base = (size_t)N * 32;
  if (tid < 32) {
    float t = 0.f;
#pragma unroll
    for (int i = 0; i < 8; ++i) t += red[i * 32 + tid];
    t /= (float)N;
    z[tid] = t;
    out[base + tid] = t;
  }
  __syncthreads();
  if (tid < 16) {
    float a = eb1[tid], b = mb1[tid];
    for (int k = 0; k < 32; ++k) {
      a += z[k] * eW1[k * 16 + tid];
      b += z[k] * mW1[k * 16 + tid];
    }
    hid[tid] = fmaxf(a, 0.f);
    hid[16 + tid] = fmaxf(b, 0.f);
  }
  __syncthreads();
  if (tid == 0) {
    float a = eb2[0];
    for (int k = 0; k < 16; ++k) a += hid[k] * eW2[k];
    out[base + 32] = 1.f / (1.f + __expf(-a));
  } else if (tid == 1) {
    float a = mb2[0];
    for (int k = 0; k < 16; ++k) a += hid[16 + k] * mW2[k];
    out[base + 33] = 1.f / (1.f + __expf(-a));
  }
}

extern "C" void kernel_launch(void* const* d_in, const int* in_sizes, int n_in,
                              void* d_out, int out_size, void* d_ws, size_t ws_size,
                              hipStream_t stream) {
  const int N = in_sizes[0] / 5;   // x is (N,5)
  const int E = in_sizes[1] / 2;   // edge_index is (2,E)
  const int M = E + N;             // CSR slots incl. self-loops

  MegaParams P;
  P.x = (const float*)d_in[0];
  const int* ei = (const int*)d_in[1];
  P.e_src = ei;
  P.e_dst = ei + E;
  P.encW = (const float*)d_in[2];
  P.encb = (const float*)d_in[3];
  for (int l = 0; l < 3; ++l) {
    const int o = 4 + 8 * l;
    P.W[l]   = (const float*)d_in[o + 0];
    P.as_[l] = (const float*)d_in[o + 1];
    P.ad_[l] = (const float*)d_in[o + 2];
    P.b_[l]  = (const float*)d_in[o + 3];
    P.g_[l]  = (const float*)d_in[o + 4];
    P.be_[l] = (const float*)d_in[o + 5];
    P.m_[l]  = (const float*)d_in[o + 6];
    P.v_[l]  = (const float*)d_in[o + 7];
  }
  P.eW1 = (const float*)d_in[28]; P.eb1 = (const float*)d_in[29];
  P.eW2 = (const float*)d_in[30]; P.eb2 = (const float*)d_in[31];
  P.mW1 = (const float*)d_in[32]; P.mb1 = (const float*)d_in[33];
  P.mW2 = (const float*)d_in[34]; P.mb2 = (const float*)d_in[35];
  P.out = (float*)d_out;
  P.N = N; P.E = E;

  // workspace layout: floats, then int region, then gpart, then barrier state
  float* wf = (float*)d_ws;
  size_t off = 0;
  P.hA = wf + off; off += (size_t)N * 64;
  P.hB = wf + off; off += (size_t)N * 64;
  P.xpb = (unsigned short*)(wf + off); off += (size_t)N * 128;  // N*256 bf16
  P.als = wf + off; off += (size_t)N * 4;
  P.ald = wf + off; off += (size_t)N * 4;
  P.pas = wf + off; off += 3 * 256;
  P.pad = wf + off; off += 3 * 256;
  int* wi = (int*)(wf + off);
  P.col = wi;                        // M
  P.rbeg = P.col + M;                // N
  P.rend = P.rbeg + N;               // N
  P.cursor = P.rend + N;             // N   } contiguous: zeroed in-kernel (mega)
  P.counter = P.cursor + N;          // 1   } or by memset (legacy)
  P.gpart = (float*)(P.counter + 1); // 256*32
  {
    uintptr_t ba = (uintptr_t)(P.gpart + 256 * 32);
    ba = (ba + 63) & ~(uintptr_t)63;  // 64B-align barrier lines
    P.bar = (int*)ba;                 // BAR_INTS ints
  }

  // ---- try the persistent mega-kernel (tree barrier), sized & checked ----
  bool done = false;
  {
    int dev = 0;
    if (hipGetDevice(&dev) == hipSuccess) {
      int numCU = 0, maxPerCU = 0;
      if (hipDeviceGetAttribute(&numCU, hipDeviceAttributeMultiprocessorCount, dev) == hipSuccess &&
          hipOccupancyMaxActiveBlocksPerMultiprocessor(&maxPerCU, (const void*)k_mega, NTHR, 0) == hipSuccess &&
          numCU > 0 && maxPerCU > 0) {
        long nblk = (long)maxPerCU * numCU;
        if (nblk > 2048) nblk = 2048;
        nblk &= ~63L;  // multiple of 64 for the tree barrier
        if (nblk >= 64) {
          void* args[] = {(void*)&P};
          if (hipLaunchCooperativeKernel((void*)k_mega, dim3((unsigned)nblk), dim3(NTHR),
                                         args, 0, stream) == hipSuccess)
            done = true;
        }
      }
    }
  }
  if (done) return;

  // ---- legacy fallback: proven R9 11-dispatch path ----
  const int T = 256;
  const int gE  = (E + T - 1) / T;
  const int gN  = (N + T - 1) / T;
  const int gGE = (N + 15) / 16;

  hipMemsetAsync(P.cursor, 0, (size_t)(N + 1) * sizeof(int) + 256 * 32 * sizeof(float), stream);
  k_count<<<gE, T, 0, stream>>>(P.e_dst, P.cursor, E);
  k_alloc<<<gN, T, 0, stream>>>(P.cursor, P.rbeg, P.rend, P.col, P.counter, N,
                                P.W[0], P.as_[0], P.ad_[0], P.W[1], P.as_[1], P.ad_[1],
                                P.W[2], P.as_[2], P.ad_[2], P.pas, P.pad);
  k_scatter<<<gE, T, 0, stream>>>(P.e_src, P.e_dst, P.cursor, P.col, E);

  k_gemm_al<256, true><<<gGE, 256, 0, stream>>>(P.x, P.encW, P.encb, P.W[0], P.pas, P.pad,
                                                P.xpb, P.als, P.ald, N);
  k_gather<64, true, false><<<N, 128, 0, stream>>>(P.xpb, P.als, P.ald, P.rbeg, P.rend, P.col,
                                                   P.b_[0], P.g_[0], P.be_[0], P.m_[0], P.v_[0],
                                                   P.hB, P.gpart, N);

  k_gemm_al<256, false><<<gGE, 256, 0, stream>>>(P.hB, P.encW, P.encb, P.W[1], P.pas + 256, P.pad + 256,
                                                 P.xpb, P.als, P.ald, N);
  k_gather<64, true, false><<<N, 128, 0, stream>>>(P.xpb, P.als, P.ald, P.rbeg, P.rend, P.col,
                                                   P.b_[1], P.g_[1], P.be_[1], P.m_[1], P.v_[1],
                                                   P.hA, P.gpart, N);

  k_gemm_al<128, false><<<gGE, 128, 0, stream>>>(P.hA, P.encW, P.encb, P.W[2], P.pas + 512, P.pad + 512,
                                                 P.xpb, P.als, P.ald, N);
  k_gather<32, false, true><<<N, 128, 0, stream>>>(P.xpb, P.als, P.ald, P.rbeg, P.rend, P.col,
                                                   P.b_[2], P.g_[2], P.be_[2], P.m_[2], P.v_[2],
                                                   P.out, P.gpart, N);

  k_heads2<<<1, 256, 0, stream>>>(P.gpart, P.eW1, P.eb1, P.eW2, P.eb2,
                                  P.mW1, P.mb1, P.mW2, P.mb2, P.out, N);
}

// Round 8
// 354.237 us; speedup vs baseline: 4.5556x; 1.8953x over previous
//
#include <hip/hip_runtime.h>
#include <math.h>

// EthicalGNN: encoder -> 3x(GAT + BN (+ReLU)) -> mean-pool -> 2 MLP heads.
// R15: back to multi-dispatch (persistent-kernel barriers cost ~48us each on
// 8-XCD MI355X: every grid sync must flush per-XCD L2 like a kernel boundary
// does - structural, R12-R14). Instead cut dispatch count 12 -> 7:
//  1. k_gemm0z : encoder gemm0 (+ als/ald from xp in LDS) + zero cursor/done
//  2. k_count  : degree count
//  3. k_alloc  : CSR region alloc (+ gpart zero)
//  4. k_scatter: CSR fill
//  5. k_fuse<256>: gather0 (LDS h) + BN/ReLU + gemm1 + als/ald   (tile=16)
//  6. k_fuse<128>: gather1 (LDS h) + BN/ReLU + gemm2 + als/ald   (tile=16)
//  7. k_ga2h   : gather2 + BN + out rows + pooled atomics + last-block heads
// gather+gemm fusion is legal because a gemm tile needs only its own 16 nodes'
// h rows (node-local); h passes through LDS, killing the hA/hB round trip.
// als/ald computed directly from xp rows in LDS (no was/wad precompute).

#define H4 4  // heads

static __device__ __forceinline__ unsigned short f2bf(float f) {
  unsigned u = __float_as_uint(f);
  u += 0x7fffu + ((u >> 16) & 1u);  // round-to-nearest-even
  return (unsigned short)(u >> 16);
}
static __device__ __forceinline__ float bfh(unsigned u) {  // low bf16 -> f32
  return __uint_as_float(u << 16);
}
static __device__ __forceinline__ float bfl(unsigned u) {  // high bf16 -> f32
  return __uint_as_float(u & 0xffff0000u);
}
static __device__ __forceinline__ float eweight(float a) {
  a = (a > 0.f) ? a : 0.2f * a;  // leaky_relu 0.2
  return __expf(a);
}

// ---------------- 1: encoder gemm0 + als/ald, plus workspace zeroing ---------
// Blocks [0,gGE): 16-node gemm tiles. Blocks [gGE,..): zero cursor/counter/done.
__global__ __launch_bounds__(256) void k_gemm0z(
    const float* __restrict__ x, const float* __restrict__ encW,
    const float* __restrict__ encb, const float* __restrict__ W,
    const float* __restrict__ as_, const float* __restrict__ ad_,
    unsigned short* __restrict__ xpb, float* __restrict__ als,
    float* __restrict__ ald, int* __restrict__ zbase, int zn, int gGE, int N) {
  __shared__ float smem[16 * 256];  // hs = smem[0:1024) ; xps = smem[0:4096)
  int tid = threadIdx.x;
  if (blockIdx.x >= gGE) {
    int i = (blockIdx.x - gGE) * 256 + tid;
    if (i < zn) zbase[i] = 0;
    return;
  }
  constexpr int K = 64, NB = 16, HC = 256;
  int n0 = blockIdx.x * NB;
  // stage h = relu? no: h = x @ encW + encb (encoder, no activation before GAT)
  for (int idx = tid; idx < NB * K; idx += 256) {
    int i = idx >> 6, j = idx & 63;
    int n = n0 + i;
    float a = 0.f;
    if (n < N) {
      a = encb[j];
#pragma unroll
      for (int k = 0; k < 5; ++k) a += x[n * 5 + k] * encW[k * 64 + j];
    }
    smem[idx] = a;
  }
  __syncthreads();
  float acc[NB];
#pragma unroll
  for (int i = 0; i < NB; ++i) acc[i] = 0.f;
  for (int k = 0; k < K; k += 4) {
    float w0 = W[(k + 0) * HC + tid];
    float w1 = W[(k + 1) * HC + tid];
    float w2 = W[(k + 2) * HC + tid];
    float w3 = W[(k + 3) * HC + tid];
#pragma unroll
    for (int i = 0; i < NB; ++i) {
      float4 hv = *(const float4*)&smem[i * K + k];
      acc[i] += hv.x * w0 + hv.y * w1 + hv.z * w2 + hv.w * w3;
    }
  }
#pragma unroll
  for (int i = 0; i < NB; ++i) {
    int n = n0 + i;
    if (n < N) xpb[(size_t)n * HC + tid] = f2bf(acc[i]);
  }
  __syncthreads();  // hs dead; xps aliases it
#pragma unroll
  for (int i = 0; i < NB; ++i) smem[i * HC + tid] = acc[i];
  __syncthreads();
  if (tid < NB * H4) {  // als/ald from xp rows: (i,h) pairs
    int i = tid >> 2, h = tid & 3;
    int n = n0 + i;
    float vs = 0.f, vd = 0.f;
    const float* xr = &smem[i * HC + h * 64];
#pragma unroll 8
    for (int c = 0; c < 64; ++c) {
      float xv = xr[c];
      vs += xv * as_[h * 64 + c];
      vd += xv * ad_[h * 64 + c];
    }
    if (n < N) { als[n * H4 + h] = vs; ald[n * H4 + h] = vd; }
  }
}

// ---------------- 2-4: CSR build ---------------------------------------------
__global__ void k_count(const int* __restrict__ dst, int* __restrict__ deg, int E) {
  int gid = blockIdx.x * blockDim.x + threadIdx.x;
  if (gid < E) atomicAdd(&deg[dst[gid]], 1);
}

__global__ void k_alloc(int* __restrict__ cursor, int* __restrict__ rbeg,
                        int* __restrict__ rend, int* __restrict__ col,
                        int* __restrict__ counter, float* __restrict__ gpart,
                        int N) {
  int gid = blockIdx.x * blockDim.x + threadIdx.x;
  int lane = threadIdx.x & 63;
  int size = (gid < N) ? (cursor[gid] + 1) : 0;  // +1 = self-loop
  int v = size;
#pragma unroll
  for (int off = 1; off < 64; off <<= 1) {
    int t = __shfl_up(v, off, 64);
    if (lane >= off) v += t;
  }
  int tot = __shfl(v, 63, 64);
  int base = 0;
  if (lane == 63) base = atomicAdd(counter, tot);
  base = __shfl(base, 63, 64);
  if (gid < N) {
    int p = base + v - size;  // exclusive prefix
    rbeg[gid] = p;
    rend[gid] = p + size;
    col[p] = gid;             // self-loop slot
    cursor[gid] = p + 1;
  }
  if (gid < 256 * 32) gpart[gid] = 0.f;  // zero pooling buckets (used in disp 7)
}

__global__ void k_scatter(const int* __restrict__ src, const int* __restrict__ dst,
                          int* __restrict__ cursor, int* __restrict__ col, int E) {
  int gid = blockIdx.x * blockDim.x + threadIdx.x;
  if (gid < E) {
    int p = atomicAdd(&cursor[dst[gid]], 1);
    col[p] = src[gid];
  }
}

// ---------------- gather inner: one wave, one node, C=64 (VPL=4) -------------
// lane = h*16 + c4; 8 edges in flight; returns normalized+head-summed channel
// values in acc[0..3] of lanes 0..15 (c0 = lane*4).
static __device__ __forceinline__ void gather_node64(
    const unsigned short* __restrict__ xpb, const float* __restrict__ als,
    float aldn, int beg, int end, const int* __restrict__ col, int lane, int h,
    float* acc) {
  float s = 0.f;
  acc[0] = acc[1] = acc[2] = acc[3] = 0.f;
  for (int cb = beg; cb < end; cb += 64) {
    int clen = end - cb;
    if (clen > 64) clen = 64;
    int cvec = (lane < clen) ? col[cb + lane] : 0;  // one coalesced load
    for (int t = 0; t < clen; t += 8) {
      int sv[8];
      float av[8];
#pragma unroll
      for (int i = 0; i < 8; ++i) {
        int idx = t + i;
        sv[i] = __shfl(cvec, (idx < clen) ? idx : 0, 64);
      }
#pragma unroll
      for (int i = 0; i < 8; ++i) av[i] = als[sv[i] * H4 + h];
      uint2 uv[8];
#pragma unroll
      for (int i = 0; i < 8; ++i)
        uv[i] = *(const uint2*)(xpb + (size_t)sv[i] * 256 + lane * 4);
#pragma unroll
      for (int i = 0; i < 8; ++i) {
        float e = (t + i < clen) ? eweight(av[i] + aldn) : 0.f;
        s += e;
        acc[0] += e * bfh(uv[i].x);
        acc[1] += e * bfl(uv[i].x);
        acc[2] += e * bfh(uv[i].y);
        acc[3] += e * bfl(uv[i].y);
      }
    }
  }
  float inv = 1.f / (s + 1e-16f);
#pragma unroll
  for (int i = 0; i < 4; ++i) {
    acc[i] *= inv;
    acc[i] += __shfl_xor(acc[i], 16, 64);  // head sum (bits 4,5 = head)
    acc[i] += __shfl_xor(acc[i], 32, 64);
  }
}

// ---------------- 5,6: fused gather_l + BN/ReLU + gemm_{l+1} + als/ald -------
// tile = 16 nodes, 256 threads = 4 waves x 4 sequential nodes. h -> LDS.
template <int HCOUT>
__global__ __launch_bounds__(256) void k_fuse(
    const unsigned short* __restrict__ xpbIn, const float* __restrict__ alsIn,
    const float* __restrict__ aldIn, const int* __restrict__ rbeg,
    const int* __restrict__ rend, const int* __restrict__ col,
    const float* __restrict__ bias, const float* __restrict__ g,
    const float* __restrict__ be, const float* __restrict__ m,
    const float* __restrict__ v, const float* __restrict__ W,
    const float* __restrict__ as_, const float* __restrict__ ad_,
    unsigned short* __restrict__ xpbOut, float* __restrict__ alsOut,
    float* __restrict__ aldOut, int N) {
  __shared__ float smem[16 * 256];  // hs = [0:1024) ; xps = [0:16*HCOUT)
  constexpr int K = 64, NB = 16;
  int tid = threadIdx.x, w = tid >> 6, lane = tid & 63, h = lane >> 4;
  int n0 = blockIdx.x * NB;
  // ---- gather: 4 nodes per wave, sequential ----
  for (int j = 0; j < 4; ++j) {
    int n = n0 + w * 4 + j;
    float acc[4];
    if (n < N) {
      float aldn = aldIn[n * H4 + h];
      gather_node64(xpbIn, alsIn, aldn, rbeg[n], rend[n], col, lane, h, acc);
      if (lane < 16) {
        int c0 = lane * 4;
#pragma unroll
        for (int i = 0; i < 4; ++i) {
          int cc = c0 + i;
          float t = acc[i] * (1.f / H4) + bias[cc];
          t = (t - m[cc]) * rsqrtf(v[cc] + 1e-5f) * g[cc] + be[cc];
          t = fmaxf(t, 0.f);  // ReLU (layers 0,1 feed the next GAT)
          smem[(w * 4 + j) * K + cc] = t;
        }
      }
    } else if (lane < 16) {
#pragma unroll
      for (int i = 0; i < 4; ++i) smem[(w * 4 + j) * K + lane * 4 + i] = 0.f;
    }
  }
  __syncthreads();
  // ---- gemm: h(LDS) @ W -> xp ----
  float acc[NB];
#pragma unroll
  for (int i = 0; i < NB; ++i) acc[i] = 0.f;
  if (HCOUT == 256 || tid < HCOUT) {
    for (int k = 0; k < K; k += 4) {
      float w0 = W[(k + 0) * HCOUT + tid];
      float w1 = W[(k + 1) * HCOUT + tid];
      float w2 = W[(k + 2) * HCOUT + tid];
      float w3 = W[(k + 3) * HCOUT + tid];
#pragma unroll
      for (int i = 0; i < NB; ++i) {
        float4 hv = *(const float4*)&smem[i * K + k];
        acc[i] += hv.x * w0 + hv.y * w1 + hv.z * w2 + hv.w * w3;
      }
    }
#pragma unroll
    for (int i = 0; i < NB; ++i) {
      int n = n0 + i;
      if (n < N) xpbOut[(size_t)n * HCOUT + tid] = f2bf(acc[i]);
    }
  }
  __syncthreads();  // hs dead; xps aliases
  if (HCOUT == 256 || tid < HCOUT) {
#pragma unroll
    for (int i = 0; i < NB; ++i) smem[i * HCOUT + tid] = acc[i];
  }
  __syncthreads();
  if (tid < NB * H4) {  // als/ald from xp rows
    constexpr int C = HCOUT / H4;
    int i = tid >> 2, hh = tid & 3;
    int n = n0 + i;
    float vs = 0.f, vd = 0.f;
    const float* xr = &smem[i * HCOUT + hh * C];
#pragma unroll 8
    for (int c = 0; c < C; ++c) {
      float xv = xr[c];
      vs += xv * as_[hh * C + c];
      vd += xv * ad_[hh * C + c];
    }
    if (n < N) { alsOut[n * H4 + hh] = vs; aldOut[n * H4 + hh] = vd; }
  }
}

// ---------------- 7: gather2 + BN + out + pool + last-block heads ------------
__global__ __launch_bounds__(256) void k_ga2h(
    const unsigned short* __restrict__ xpbIn, const float* __restrict__ alsIn,
    const float* __restrict__ aldIn, const int* __restrict__ rbeg,
    const int* __restrict__ rend, const int* __restrict__ col,
    const float* __restrict__ bias, const float* __restrict__ g,
    const float* __restrict__ be, const float* __restrict__ m,
    const float* __restrict__ v, float* __restrict__ out,
    float* __restrict__ gpart, int* __restrict__ done, int ntiles,
    const float* __restrict__ eW1, const float* __restrict__ eb1,
    const float* __restrict__ eW2, const float* __restrict__ eb2,
    const float* __restrict__ mW1, const float* __restrict__ mb1,
    const float* __restrict__ mW2, const float* __restrict__ mb2, int N) {
  __shared__ float smem[320];  // heads: red[256] z[32] hid[32]
  __shared__ int amlast;
  int tid = threadIdx.x, w = tid >> 6, lane = tid & 63, h = lane >> 4;
  int n0 = blockIdx.x * 16;
  for (int j = 0; j < 4; ++j) {  // 4 nodes per wave, C=32 (VPL=2)
    int n = n0 + w * 4 + j;
    if (n >= N) continue;
    float aldn = aldIn[n * H4 + h];
    int beg = rbeg[n], end = rend[n];
    float s = 0.f, a0 = 0.f, a1 = 0.f;
    for (int cb = beg; cb < end; cb += 64) {
      int clen = end - cb;
      if (clen > 64) clen = 64;
      int cvec = (lane < clen) ? col[cb + lane] : 0;
      for (int t = 0; t < clen; t += 8) {
        int sv[8];
        float av[8];
#pragma unroll
        for (int i = 0; i < 8; ++i) {
          int idx = t + i;
          sv[i] = __shfl(cvec, (idx < clen) ? idx : 0, 64);
        }
#pragma unroll
        for (int i = 0; i < 8; ++i) av[i] = alsIn[sv[i] * H4 + h];
        unsigned uw[8];
#pragma unroll
        for (int i = 0; i < 8; ++i)
          uw[i] = *(const unsigned*)(xpbIn + (size_t)sv[i] * 128 + lane * 2);
#pragma unroll
        for (int i = 0; i < 8; ++i) {
          float e = (t + i < clen) ? eweight(av[i] + aldn) : 0.f;
          s += e;
          a0 += e * bfh(uw[i]);
          a1 += e * bfl(uw[i]);
        }
      }
    }
    float inv = 1.f / (s + 1e-16f);
    a0 *= inv; a1 *= inv;
    a0 += __shfl_xor(a0, 16, 64); a0 += __shfl_xor(a0, 32, 64);
    a1 += __shfl_xor(a1, 16, 64); a1 += __shfl_xor(a1, 32, 64);
    if (lane < 16) {
      int c0 = lane * 2;
      float o0 = a0 * (1.f / H4) + bias[c0];
      o0 = (o0 - m[c0]) * rsqrtf(v[c0] + 1e-5f) * g[c0] + be[c0];
      int c1 = c0 + 1;
      float o1 = a1 * (1.f / H4) + bias[c1];
      o1 = (o1 - m[c1]) * rsqrtf(v[c1] + 1e-5f) * g[c1] + be[c1];
      *(float2*)&out[(size_t)n * 32 + c0] = make_float2(o0, o1);
      atomicAdd(&gpart[(n & 255) * 32 + c0], o0);
      atomicAdd(&gpart[(n & 255) * 32 + c1], o1);
    }
  }
  // last block to finish runs the heads (atomics drained by syncthreads)
  __syncthreads();
  if (tid == 0) {
    __threadfence();
    amlast = (atomicAdd(done, 1) == ntiles - 1) ? 1 : 0;
  }
  __syncthreads();
  if (!amlast) return;
  __threadfence();
  float* red = smem;
  float* z = smem + 256;
  float* hid = smem + 288;
  int c = tid & 31;
  float s = 0.f;
  for (int b = tid >> 5; b < 256; b += 8)
    s += __hip_atomic_load(&gpart[b * 32 + c], __ATOMIC_RELAXED,
                           __HIP_MEMORY_SCOPE_AGENT);
  red[tid] = s;
  __syncthreads();
  size_t base = (size_t)N * 32;
  if (tid < 32) {
    float t = 0.f;
#pragma unroll
    for (int i = 0; i < 8; ++i) t += red[i * 32 + tid];
    t /= (float)N;
    z[tid] = t;
    out[base + tid] = t;  // graph_emb
  }
  __syncthreads();
  if (tid < 16) {
    float a = eb1[tid], b = mb1[tid];
    for (int k = 0; k < 32; ++k) {
      a += z[k] * eW1[k * 16 + tid];
      b += z[k] * mW1[k * 16 + tid];
    }
    hid[tid] = fmaxf(a, 0.f);
    hid[16 + tid] = fmaxf(b, 0.f);
  }
  __syncthreads();
  if (tid == 0) {
    float a = eb2[0];
    for (int k = 0; k < 16; ++k) a += hid[k] * eW2[k];
    out[base + 32] = 1.f / (1.f + __expf(-a));
  } else if (tid == 1) {
    float a = mb2[0];
    for (int k = 0; k < 16; ++k) a += hid[16 + k] * mW2[k];
    out[base + 33] = 1.f / (1.f + __expf(-a));
  }
}

extern "C" void kernel_launch(void* const* d_in, const int* in_sizes, int n_in,
                              void* d_out, int out_size, void* d_ws, size_t ws_size,
                              hipStream_t stream) {
  const int N = in_sizes[0] / 5;   // x is (N,5)
  const int E = in_sizes[1] / 2;   // edge_index is (2,E)
  const int M = E + N;             // CSR slots incl. self-loops

  const float* x = (const float*)d_in[0];
  const int* ei = (const int*)d_in[1];
  const int* e_src = ei;
  const int* e_dst = ei + E;
  const float* encW = (const float*)d_in[2];
  const float* encb = (const float*)d_in[3];
  const float* Wl[3]; const float* asl[3]; const float* adl[3]; const float* bl[3];
  const float* gl[3]; const float* bel[3]; const float* ml[3]; const float* vl[3];
  for (int l = 0; l < 3; ++l) {
    const int o = 4 + 8 * l;
    Wl[l]  = (const float*)d_in[o + 0];
    asl[l] = (const float*)d_in[o + 1];
    adl[l] = (const float*)d_in[o + 2];
    bl[l]  = (const float*)d_in[o + 3];
    gl[l]  = (const float*)d_in[o + 4];
    bel[l] = (const float*)d_in[o + 5];
    ml[l]  = (const float*)d_in[o + 6];
    vl[l]  = (const float*)d_in[o + 7];
  }
  const float* eW1 = (const float*)d_in[28];
  const float* eb1 = (const float*)d_in[29];
  const float* eW2 = (const float*)d_in[30];
  const float* eb2 = (const float*)d_in[31];
  const float* mW1 = (const float*)d_in[32];
  const float* mb1 = (const float*)d_in[33];
  const float* mW2 = (const float*)d_in[34];
  const float* mb2 = (const float*)d_in[35];

  float* out = (float*)d_out;

  // workspace: xpbA, xpbB (bf16 rows), alsA/aldA/alsB/aldB, int CSR region
  float* wf = (float*)d_ws;
  size_t off = 0;
  unsigned short* xpbA = (unsigned short*)(wf + off); off += (size_t)N * 128;
  unsigned short* xpbB = (unsigned short*)(wf + off); off += (size_t)N * 128;
  float* alsA = wf + off; off += (size_t)N * 4;
  float* aldA = wf + off; off += (size_t)N * 4;
  float* alsB = wf + off; off += (size_t)N * 4;
  float* aldB = wf + off; off += (size_t)N * 4;
  int* wi = (int*)(wf + off);
  int* col     = wi;                     // M
  int* rbeg    = col + M;                // N
  int* rend    = rbeg + N;               // N
  int* cursor  = rend + N;               // N   } contiguous, zeroed by k_gemm0z
  int* counter = cursor + N;             // 1   }
  int* done    = counter + 1;            // 1   }
  float* gpart = (float*)(done + 1);     // 256*32, zeroed by k_alloc

  const int T = 256;
  const int gE  = (E + T - 1) / T;
  const int gN  = (N + T - 1) / T;
  const int gGE = (N + 15) / 16;          // 16-node tiles
  const int zn  = N + 2;                  // cursor + counter + done
  const int zb  = (zn + T - 1) / T;

  // 1: encoder gemm0 (+als/ald) and workspace zeroing, one dispatch
  k_gemm0z<<<gGE + zb, T, 0, stream>>>(x, encW, encb, Wl[0], asl[0], adl[0],
                                       xpbA, alsA, aldA, cursor, zn, gGE, N);
  // 2-4: CSR build
  k_count<<<gE, T, 0, stream>>>(e_dst, cursor, E);
  k_alloc<<<gN, T, 0, stream>>>(cursor, rbeg, rend, col, counter, gpart, N);
  k_scatter<<<gE, T, 0, stream>>>(e_src, e_dst, cursor, col, E);
  // 5: gather0 + BN/ReLU + gemm1 + als/ald
  k_fuse<256><<<gGE, T, 0, stream>>>(xpbA, alsA, aldA, rbeg, rend, col,
                                     bl[0], gl[0], bel[0], ml[0], vl[0],
                                     Wl[1], asl[1], adl[1],
                                     xpbB, alsB, aldB, N);
  // 6: gather1 + BN/ReLU + gemm2 + als/ald
  k_fuse<128><<<gGE, T, 0, stream>>>(xpbB, alsB, aldB, rbeg, rend, col,
                                     bl[1], gl[1], bel[1], ml[1], vl[1],
                                     Wl[2], asl[2], adl[2],
                                     xpbA, alsA, aldA, N);
  // 7: gather2 + BN + out + pool + last-block heads
  k_ga2h<<<gGE, T, 0, stream>>>(xpbA, alsA, aldA, rbeg, rend, col,
                                bl[2], gl[2], bel[2], ml[2], vl[2],
                                out, gpart, done, gGE,
                                eW1, eb1, eW2, eb2, mW1, mb1, mW2, mb2, N);
}